// Round 2
// baseline (1128.061 us; speedup 1.0000x reference)
//
#include <hip/hip_runtime.h>
#include <cstdint>
#include <cstddef>

#define NB    8192
#define DD    768
#define NE    16
#define EDD   1536
#define KTOP  100
#define MAXT  8192
#define CAND_MAX 160
#define K1BLK 2048          // k1a blocks (4 tokens each)

typedef __attribute__((ext_vector_type(4))) float f32x4;
typedef __attribute__((ext_vector_type(8))) short bf16x8;

__device__ __forceinline__ unsigned short f2bf(float v) {
    unsigned int u = __float_as_uint(v);
    u += 0x7FFFu + ((u >> 16) & 1u);   // RNE to bf16
    return (unsigned short)(u >> 16);
}
__device__ __forceinline__ float bf2f(unsigned short h) {
    return __uint_as_float(((unsigned int)h) << 16);
}
__device__ __forceinline__ void async16(const void* g, void* l) {
    __builtin_amdgcn_global_load_lds(
        (const __attribute__((address_space(1))) unsigned int*)g,
        (__attribute__((address_space(3))) unsigned int*)l, 16, 0, 0);
}

// ---------------------------------------------------------------- K0: converts
__global__ __launch_bounds__(256) void k0_split_w(
    const float* __restrict__ w, unsigned short* __restrict__ hi,
    unsigned short* __restrict__ lo)
{
    const int i = blockIdx.x * 256 + threadIdx.x;   // n4 = 4718592 exact
    const float4 v = reinterpret_cast<const float4*>(w)[i];
    ushort4 h, l;
    h.x = f2bf(v.x); l.x = f2bf(v.x - bf2f(h.x));
    h.y = f2bf(v.y); l.y = f2bf(v.y - bf2f(h.y));
    h.z = f2bf(v.z); l.z = f2bf(v.z - bf2f(h.z));
    h.w = f2bf(v.w); l.w = f2bf(v.w - bf2f(h.w));
    reinterpret_cast<ushort4*>(hi)[i] = h;
    reinterpret_cast<ushort4*>(lo)[i] = l;
}

__global__ __launch_bounds__(256) void k0_cvt16(
    const float* __restrict__ src, unsigned short* __restrict__ dst)
{
    const int i = blockIdx.x * 256 + threadIdx.x;
    const float4 v = reinterpret_cast<const float4*>(src)[i];
    ushort4 h;
    h.x = f2bf(v.x); h.y = f2bf(v.y); h.z = f2bf(v.z); h.w = f2bf(v.w);
    reinterpret_cast<ushort4*>(dst)[i] = h;
}

// ---------------------------------------------------------------- K1a: gate
// one wave per token; fp64 logits/softmax/renorm; LDS-local ranks, no global atomics.
__global__ __launch_bounds__(256) void k1_gate(
    const float* __restrict__ x, const float* __restrict__ gate_W,
    const float* __restrict__ gate_b, const float* __restrict__ b_gate,
    int* __restrict__ eids, double* __restrict__ entw,
    int* __restrict__ rnk, int* __restrict__ blk_cnt)
{
    __shared__ int cnt[NE];
    const int wid  = threadIdx.x >> 6;
    const int lane = threadIdx.x & 63;
    const int blk  = blockIdx.x;
    const int tok  = blk * 4 + wid;

    if (threadIdx.x < NE) cnt[threadIdx.x] = 0;
    __syncthreads();

    double xv[12];
#pragma unroll
    for (int j = 0; j < 12; ++j) {
        const int k = j * 64 + lane;
        xv[j] = (double)x[(size_t)tok * DD + k] - (double)b_gate[k];
    }

    double myLogit = -1.0e300;
    for (int e = 0; e < NE; ++e) {
        double d = 0.0;
#pragma unroll
        for (int j = 0; j < 12; ++j)
            d += xv[j] * (double)gate_W[e * DD + j * 64 + lane];
#pragma unroll
        for (int off = 32; off > 0; off >>= 1)
            d += __shfl_xor(d, off);
        if (lane == e) myLogit = d + (double)gate_b[e];
    }

    double m = myLogit;
#pragma unroll
    for (int off = 8; off > 0; off >>= 1) {
        double o = __shfl_xor(m, off); m = (o > m) ? o : m;
    }
    double p = exp(myLogit - m);
    double ssum = p;
#pragma unroll
    for (int off = 8; off > 0; off >>= 1) ssum += __shfl_xor(ssum, off);
    const double score = p / ssum;

    const bool lt16 = (lane < NE);
    double m1 = score;
#pragma unroll
    for (int off = 8; off > 0; off >>= 1) {
        double o = __shfl_xor(m1, off); m1 = (o > m1) ? o : m1;
    }
    unsigned long long b0 = __ballot(lt16 && (score == m1));
    const int i0 = __ffsll(b0) - 1;
    double sc2 = (lane == i0) ? -1.0 : score;
    double m2 = sc2;
#pragma unroll
    for (int off = 8; off > 0; off >>= 1) {
        double o = __shfl_xor(m2, off); m2 = (o > m2) ? o : m2;
    }
    unsigned long long b1 = __ballot(lt16 && (sc2 == m2));
    const int i1 = __ffsll(b1) - 1;

    if (lane == 0) {
        const double w0 = 1.0 / (1.0 + exp(m2 - m1));  // softmax([s0,s1])
        const double w1 = 1.0 - w0;
        eids[tok * 2 + 0] = i0;
        eids[tok * 2 + 1] = i1;
        entw[tok * 2 + 0] = w0;
        entw[tok * 2 + 1] = w1;
        rnk[tok * 2 + 0] = atomicAdd(&cnt[i0], 1);
        rnk[tok * 2 + 1] = atomicAdd(&cnt[i1], 1);
    }
    __syncthreads();
    if (threadIdx.x < NE) blk_cnt[threadIdx.x * K1BLK + blk] = cnt[threadIdx.x];
}

// ---------------------------------------------------------------- K1b: scan
__global__ __launch_bounds__(256) void k1_scan(
    const int* __restrict__ blk_cnt, int* __restrict__ blk_off,
    int* __restrict__ counts)
{
    __shared__ int tsum[256];
    const int t = threadIdx.x;
    for (int e = 0; e < NE; ++e) {
        int loc[8]; int s = 0;
#pragma unroll
        for (int i = 0; i < 8; ++i) { loc[i] = s; s += blk_cnt[e * K1BLK + t * 8 + i]; }
        tsum[t] = s;
        __syncthreads();
        for (int off = 1; off < 256; off <<= 1) {
            const int u = (t >= off) ? tsum[t - off] : 0;
            __syncthreads();
            tsum[t] += u;
            __syncthreads();
        }
        const int excl = tsum[t] - s;
#pragma unroll
        for (int i = 0; i < 8; ++i) blk_off[e * K1BLK + t * 8 + i] = excl + loc[i];
        if (t == 255) counts[e] = tsum[255];
        __syncthreads();
    }
}

// ---------------------------------------------------------------- K1c: scatter
__global__ __launch_bounds__(256) void k1_scatter(
    const int* __restrict__ eids, const int* __restrict__ rnk,
    const int* __restrict__ blk_off, int* __restrict__ lists)
{
    const int i = blockIdx.x * 256 + threadIdx.x;   // 16384 entries
    const int e = eids[i];
    const int blk = i >> 3;                          // token>>2
    lists[e * MAXT + blk_off[e * K1BLK + blk] + rnk[i]] = i;
}

// ------------------------------------------------- K2: grouped expert GEMM
// 128x128 tile, BK=64, split-bf16 (hh+hl+lh) MFMA 16x16x32.
// FAST: B via global_load_lds from pre-split whi/wlo (inverse-swizzled source).
template<bool FAST>
__global__ __launch_bounds__(256, 2) void k2_encode(
    const float* __restrict__ x, const float* __restrict__ b_dec,
    const float* __restrict__ expert_W,
    const unsigned short* __restrict__ whi, const unsigned short* __restrict__ wlo,
    const float* __restrict__ expert_b,
    const int* __restrict__ counts, const int* __restrict__ lists,
    const double* __restrict__ entw, unsigned short* __restrict__ fbuf)
{
    const int e = blockIdx.z;
    const int cnt = counts[e];
    const int mbase = blockIdx.x * 128;     // mtile fastest -> B-tile L2 locality
    if (mbase >= cnt) return;
    const int rows = min(128, cnt - mbase);
    const int nbase = blockIdx.y * 128;

    __shared__ char smem[65536];
    char* Ahi = smem;
    char* Alo = smem + 16384;
    char* Bhi = smem + 32768;
    char* Blo = smem + 49152;

    const int t = threadIdx.x;
    const int lane = t & 63;
    const int wid = t >> 6;
    const int wm = wid >> 1, wn = wid & 1;
    const int l15 = lane & 15, q = lane >> 4;
    const int kq = t & 15, rg = t >> 4;

    int tok_r[8];
#pragma unroll
    for (int j = 0; j < 8; ++j) {
        const int r = rg * 8 + j;
        tok_r[j] = (r < rows) ? (lists[e * MAXT + mbase + r] >> 1) : -1;
    }

    const int brow_l = lane >> 3;  // row-in-instr for async B staging
    const int cgx = lane & 7;      // lds chunk for this lane

    f32x4 acc[4][4];
#pragma unroll
    for (int a = 0; a < 4; ++a)
#pragma unroll
        for (int b = 0; b < 4; ++b)
            acc[a][b] = f32x4{0.f, 0.f, 0.f, 0.f};

    for (int s = 0; s < 12; ++s) {
        if constexpr (FAST) {
#pragma unroll
            for (int j = 0; j < 4; ++j) {
                const int slot = wid * 4 + j;
                const int brow = (slot << 3) + brow_l;
                const size_t sbyte = (size_t)(e * EDD + nbase + brow) * (DD * 2)
                                   + (size_t)s * 128 + (size_t)((cgx ^ (brow & 7)) << 4);
                async16((const char*)whi + sbyte, Bhi + (slot << 10));
                async16((const char*)wlo + sbyte, Blo + (slot << 10));
            }
        }
        const float4 bd4 = *reinterpret_cast<const float4*>(b_dec + s * 64 + kq * 4);
#pragma unroll
        for (int j = 0; j < 8; ++j) {
            const int r = rg * 8 + j;
            float4 av = make_float4(0.f, 0.f, 0.f, 0.f);
            if (tok_r[j] >= 0) {
                av = *reinterpret_cast<const float4*>(x + (size_t)tok_r[j] * DD + s * 64 + kq * 4);
                av.x -= bd4.x; av.y -= bd4.y; av.z -= bd4.z; av.w -= bd4.w;
            }
            const int boff = (r * 128 + kq * 8) ^ ((r & 7) << 4);
            ushort4 ah4, al4;
            {
                unsigned short h;
                h = f2bf(av.x); ah4.x = h; al4.x = f2bf(av.x - bf2f(h));
                h = f2bf(av.y); ah4.y = h; al4.y = f2bf(av.y - bf2f(h));
                h = f2bf(av.z); ah4.z = h; al4.z = f2bf(av.z - bf2f(h));
                h = f2bf(av.w); ah4.w = h; al4.w = f2bf(av.w - bf2f(h));
            }
            *reinterpret_cast<ushort4*>(Ahi + boff) = ah4;
            *reinterpret_cast<ushort4*>(Alo + boff) = al4;
            if constexpr (!FAST) {
                const float4 bv = *reinterpret_cast<const float4*>(
                    expert_W + ((size_t)e * EDD + nbase + r) * DD + s * 64 + kq * 4);
                ushort4 bh4, bl4;
                unsigned short h;
                h = f2bf(bv.x); bh4.x = h; bl4.x = f2bf(bv.x - bf2f(h));
                h = f2bf(bv.y); bh4.y = h; bl4.y = f2bf(bv.y - bf2f(h));
                h = f2bf(bv.z); bh4.z = h; bl4.z = f2bf(bv.z - bf2f(h));
                h = f2bf(bv.w); bh4.w = h; bl4.w = f2bf(bv.w - bf2f(h));
                *reinterpret_cast<ushort4*>(Bhi + boff) = bh4;
                *reinterpret_cast<ushort4*>(Blo + boff) = bl4;
            }
        }
        __syncthreads();

#pragma unroll
        for (int ks = 0; ks < 2; ++ks) {
            bf16x8 ah[4], al[4], bh[4], bl[4];
#pragma unroll
            for (int fm = 0; fm < 4; ++fm) {
                const int row = wm * 64 + fm * 16 + l15;
                const int boff = (row * 128 + ((ks * 64 + q * 16) ^ ((row & 7) << 4)));
                ah[fm] = *reinterpret_cast<const bf16x8*>(Ahi + boff);
                al[fm] = *reinterpret_cast<const bf16x8*>(Alo + boff);
            }
#pragma unroll
            for (int fn = 0; fn < 4; ++fn) {
                const int row = wn * 64 + fn * 16 + l15;
                const int boff = (row * 128 + ((ks * 64 + q * 16) ^ ((row & 7) << 4)));
                bh[fn] = *reinterpret_cast<const bf16x8*>(Bhi + boff);
                bl[fn] = *reinterpret_cast<const bf16x8*>(Blo + boff);
            }
#pragma unroll
            for (int fm = 0; fm < 4; ++fm)
#pragma unroll
                for (int fn = 0; fn < 4; ++fn) {
                    acc[fm][fn] = __builtin_amdgcn_mfma_f32_16x16x32_bf16(ah[fm], bh[fn], acc[fm][fn], 0, 0, 0);
                    acc[fm][fn] = __builtin_amdgcn_mfma_f32_16x16x32_bf16(ah[fm], bl[fn], acc[fm][fn], 0, 0, 0);
                    acc[fm][fn] = __builtin_amdgcn_mfma_f32_16x16x32_bf16(al[fm], bh[fn], acc[fm][fn], 0, 0, 0);
                }
        }
        __syncthreads();
    }

    // epilogue: C/D layout col=lane&15, row=(lane>>4)*4+reg; bias+relu+renorm; bf16 out
#pragma unroll
    for (int fm = 0; fm < 4; ++fm) {
#pragma unroll
        for (int r = 0; r < 4; ++r) {
            const int ml = wm * 64 + fm * 16 + q * 4 + r;
            if (ml >= rows) continue;
            const int ent = lists[e * MAXT + mbase + ml];
            const float ren = (float)entw[ent];
            unsigned short* fout = fbuf + (size_t)ent * EDD + nbase;
#pragma unroll
            for (int fn = 0; fn < 4; ++fn) {
                const int nl = wn * 64 + fn * 16 + l15;
                float v = acc[fm][fn][r] + expert_b[e * EDD + nbase + nl];
                v = fmaxf(v, 0.f) * ren;
                fout[nl] = f2bf(v);
            }
        }
    }
}

// --------------------------- K3: per-token exact top-100 + fused decode
// bf16 f-values; 2-pass radix on 16-bit keys; conf = bucket>=T+2 (provably
// top-100); buckets {T-1,T,T+1} re-evaluated in fp64 (wave-parallel).
template<int DEC16>
__global__ __launch_bounds__(256) void k3_topk_decode(
    const float* __restrict__ x, const float* __restrict__ b_dec,
    const float* __restrict__ expert_W, const float* __restrict__ expert_b,
    const int* __restrict__ eids, const double* __restrict__ entw,
    const unsigned short* __restrict__ fbuf,
    const float* __restrict__ decoder, const unsigned short* __restrict__ dec16,
    float* __restrict__ out)
{
    const int tok = blockIdx.x;
    const int t = threadIdx.x;

    __shared__ unsigned short fv[3072];
    __shared__ unsigned int hist[256];
    __shared__ int hb_s, T_s, rem_s, tz_s, nsel_s, ncand_s, total_s;
    __shared__ int   sel_didx[KTOP];
    __shared__ float sel_act[KTOP];
    __shared__ int    cidx[CAND_MAX];
    __shared__ double cval[CAND_MAX];

    const unsigned int* frow = reinterpret_cast<const unsigned int*>(fbuf + (size_t)tok * 2 * EDD);
#pragma unroll
    for (int i = 0; i < 6; ++i)
        reinterpret_cast<unsigned int*>(fv)[t + 256 * i] = frow[t + 256 * i];
    if (t == 0) { tz_s = 0; nsel_s = 0; ncand_s = 0; }
    hist[t] = 0u;
    __syncthreads();

    // pass 1: top byte
#pragma unroll
    for (int i = 0; i < 12; ++i) {
        const unsigned int u = fv[t + 256 * i];
        if (u) atomicAdd(&hist[u >> 8], 1u);
    }
    __syncthreads();
    if (t == 0) {
        unsigned int cum = 0; int v = 255;
        for (; v >= 0; --v) { const unsigned int c = hist[v]; if (cum + c >= KTOP) break; cum += c; }
        if (v < 0) tz_s = 1;
        else { hb_s = v; rem_s = KTOP - (int)cum; }
    }
    __syncthreads();

    if (!tz_s) {
        hist[t] = 0u;
        __syncthreads();
        const unsigned int hb = (unsigned int)hb_s;
#pragma unroll
        for (int i = 0; i < 12; ++i) {
            const unsigned int u = fv[t + 256 * i];
            if (u && (u >> 8) == hb) atomicAdd(&hist[u & 255u], 1u);
        }
        __syncthreads();
        if (t == 0) {
            const int rem = rem_s; unsigned int cum = 0; int v = 255;
            for (; v >= 0; --v) { const unsigned int c = hist[v]; if (cum + c >= (unsigned int)rem) break; cum += c; }
            T_s = (hb_s << 8) | v;
        }
        __syncthreads();
    }

    if (tz_s) {
        // take all positives (others are exact zeros)
#pragma unroll
        for (int i = 0; i < 12; ++i) {
            const int j = t + 256 * i;
            const unsigned int u = fv[j];
            if (u) {
                const int p = atomicAdd(&nsel_s, 1);
                const int slot = (j >= EDD) ? 1 : 0;
                const int n = j - slot * EDD;
                sel_didx[p] = eids[tok * 2 + slot] * EDD + n;
                sel_act[p] = bf2f((unsigned short)u);
            }
        }
        __syncthreads();
        if (t == 0) total_s = nsel_s;
        __syncthreads();
    } else {
        const int T = T_s;
#pragma unroll
        for (int i = 0; i < 12; ++i) {
            const int j = t + 256 * i;
            const unsigned int u = fv[j];
            if ((int)u >= T + 2) {
                const int p = atomicAdd(&nsel_s, 1);
                const int slot = (j >= EDD) ? 1 : 0;
                const int n = j - slot * EDD;
                sel_didx[p] = eids[tok * 2 + slot] * EDD + n;
                sel_act[p] = bf2f((unsigned short)u);
            } else if (u != 0u && (int)u + 1 >= T) {
                const int c = atomicAdd(&ncand_s, 1);
                if (c < CAND_MAX) cidx[c] = j;
            }
        }
        __syncthreads();

        // fp64 re-evaluation of candidates, one wave per candidate
        {
            const int ncand = min(ncand_s, CAND_MAX);
            const int wv = t >> 6, lane = t & 63;
            for (int c = wv; c < ncand; c += 4) {
                const int j = cidx[c];
                const int slot = (j >= EDD) ? 1 : 0;
                const int n = j - slot * EDD;
                const int ee = eids[tok * 2 + slot];
                const float* wr = expert_W + ((size_t)ee * EDD + n) * DD;
                const float* xr = x + (size_t)tok * DD;
                double d = 0.0;
#pragma unroll
                for (int jj = 0; jj < 12; ++jj) {
                    const int k = jj * 64 + lane;
                    d += ((double)xr[k] - (double)b_dec[k]) * (double)wr[k];
                }
#pragma unroll
                for (int off = 32; off > 0; off >>= 1) d += __shfl_xor(d, off);
                if (lane == 0) {
                    double z = d + (double)expert_b[ee * EDD + n];
                    if (z < 0.0) z = 0.0;
                    cval[c] = z * entw[tok * 2 + slot];
                }
            }
        }
        __syncthreads();

        if (t == 0) {
            const int nconf = nsel_s;
            const int ncand = min(ncand_s, CAND_MAX);
            int need = KTOP - nconf;
            if (need > ncand) need = ncand;
            if (need < 0) need = 0;
            for (int c = 0; c < need; ++c) {   // (value desc, dict idx asc)
                double bv = -1.0; int bdi = 0x7FFFFFFF; int bi = -1;
                for (int i = 0; i < ncand; ++i) {
                    const int j = cidx[i];
                    if (j < 0) continue;
                    const int slot = (j >= EDD) ? 1 : 0;
                    const int n = j - slot * EDD;
                    const int di = eids[tok * 2 + slot] * EDD + n;
                    const double v = cval[i];
                    if (v > bv || (v == bv && di < bdi)) { bv = v; bdi = di; bi = i; }
                }
                cidx[bi] = -1;
                sel_didx[nconf + c] = bdi;
                sel_act[nconf + c] = (float)bv;
            }
            total_s = nconf + need;
        }
        __syncthreads();
    }

    // fused decode: x_hat = sum a_k * decoder[idx_k] + b_dec
    const int total = total_s;
    float a0 = 0.f, a1 = 0.f, a2 = 0.f;
    for (int k = 0; k < total; ++k) {
        const float a = sel_act[k];
        if (DEC16) {
            const unsigned short* dr = dec16 + (size_t)sel_didx[k] * DD;
            a0 += a * bf2f(dr[t]);
            a1 += a * bf2f(dr[t + 256]);
            a2 += a * bf2f(dr[t + 512]);
        } else {
            const float* dr = decoder + (size_t)sel_didx[k] * DD;
            a0 += a * dr[t];
            a1 += a * dr[t + 256];
            a2 += a * dr[t + 512];
        }
    }
    out[(size_t)tok * DD + t]       = a0 + b_dec[t];
    out[(size_t)tok * DD + t + 256] = a1 + b_dec[t + 256];
    out[(size_t)tok * DD + t + 512] = a2 + b_dec[t + 512];
}

// sentinel fill if workspace is too small (diagnosable: absmax ~ 12345)
__global__ void k_sentinel(float* __restrict__ out, int n) {
    int i = blockIdx.x * blockDim.x + threadIdx.x;
    if (i < n) out[i] = 12345.0f;
}

extern "C" void kernel_launch(void* const* d_in, const int* in_sizes, int n_in,
                              void* d_out, int out_size, void* d_ws, size_t ws_size,
                              hipStream_t stream)
{
    (void)in_sizes; (void)n_in;
    const float* x        = (const float*)d_in[0];
    const float* gate_W   = (const float*)d_in[1];
    const float* gate_b   = (const float*)d_in[2];
    const float* b_gate   = (const float*)d_in[3];
    const float* b_dec    = (const float*)d_in[4];
    const float* expert_W = (const float*)d_in[5];
    const float* expert_b = (const float*)d_in[6];
    const float* decoder  = (const float*)d_in[7];
    float* out = (float*)d_out;

    char* ws = (char*)d_ws;
    const size_t off_blkcnt = 256;
    const size_t off_blkoff = off_blkcnt + (size_t)NE * K1BLK * 4;   // +128K
    const size_t off_rnk    = off_blkoff + (size_t)NE * K1BLK * 4;   // +128K
    const size_t off_eids   = off_rnk    + (size_t)NB * 2 * 4;
    const size_t off_entw   = off_eids   + (size_t)NB * 2 * 4;
    const size_t off_lists  = off_entw   + (size_t)NB * 2 * 8;
    const size_t off_fbuf   = off_lists  + (size_t)NE * MAXT * 4;
    const size_t base_end   = off_fbuf   + (size_t)NB * 2 * EDD * 2;  // ~51.4 MB
    const size_t WSZ        = (size_t)NE * EDD * DD * 2;              // 37.75 MB
    const size_t need_T0 = base_end + 3 * WSZ;   // fast k2 + bf16 decoder
    const size_t need_T1 = base_end + 2 * WSZ;   // fast k2, fp32 decoder
    const size_t need_T2 = base_end + 1 * WSZ;   // slow k2, bf16 decoder

    if (ws_size < need_T2) {
        k_sentinel<<<(out_size + 255) / 256, 256, 0, stream>>>(out, out_size);
        return;
    }
    const bool fast  = (ws_size >= need_T1);
    const bool dec16en = (ws_size >= need_T0) || !fast;

    int*            blk_cnt = (int*)(ws + off_blkcnt);
    int*            blk_off = (int*)(ws + off_blkoff);
    int*            rnk     = (int*)(ws + off_rnk);
    int*            eids    = (int*)(ws + off_eids);
    double*         entw    = (double*)(ws + off_entw);
    int*            lists   = (int*)(ws + off_lists);
    int*            counts  = (int*)ws;
    unsigned short* fbuf    = (unsigned short*)(ws + off_fbuf);
    unsigned short* whi     = (unsigned short*)(ws + base_end);
    unsigned short* wlo     = (unsigned short*)(ws + base_end + WSZ);
    unsigned short* dec16v  = fast ? (unsigned short*)(ws + base_end + 2 * WSZ)
                                   : (unsigned short*)(ws + base_end);

    const int n4blocks = (NE * EDD * DD / 4) / 256;   // 18432

    if (fast)
        k0_split_w<<<n4blocks, 256, 0, stream>>>(expert_W, whi, wlo);
    if (dec16en)
        k0_cvt16<<<n4blocks, 256, 0, stream>>>(decoder, dec16v);

    k1_gate<<<K1BLK, 256, 0, stream>>>(x, gate_W, gate_b, b_gate, eids, entw, rnk, blk_cnt);
    k1_scan<<<1, 256, 0, stream>>>(blk_cnt, blk_off, counts);
    k1_scatter<<<NB * 2 / 256, 256, 0, stream>>>(eids, rnk, blk_off, lists);

    dim3 g2(MAXT / 128, EDD / 128, NE);   // (mtile=64, ntile=12, e=16), early-exit
    if (fast)
        k2_encode<true><<<g2, 256, 0, stream>>>(x, b_dec, expert_W, whi, wlo,
                                                expert_b, counts, lists, entw, fbuf);
    else
        k2_encode<false><<<g2, 256, 0, stream>>>(x, b_dec, expert_W, whi, wlo,
                                                 expert_b, counts, lists, entw, fbuf);

    if (dec16en)
        k3_topk_decode<1><<<NB, 256, 0, stream>>>(x, b_dec, expert_W, expert_b, eids,
                                                  entw, fbuf, decoder, dec16v, out);
    else
        k3_topk_decode<0><<<NB, 256, 0, stream>>>(x, b_dec, expert_W, expert_b, eids,
                                                  entw, fbuf, decoder, dec16v, out);
}

// Round 3
// 492.661 us; speedup vs baseline: 2.2897x; 2.2897x over previous
//
#include <hip/hip_runtime.h>
#include <hip/hip_fp16.h>
#include <cstdint>
#include <cstddef>

#define NB    8192
#define DD    768
#define NE    16
#define EDD   1536
#define KTOP  100
#define MAXT  8192
#define CAND_MAX 256
#define K1BLK 2048
#define NSTEP 12
#define BKBYTES 128      // 64 k * 2B
#define CONF_ULP 41
#define BAND_ULP 40

typedef __attribute__((ext_vector_type(4))) float f32x4;
typedef __attribute__((ext_vector_type(8))) short bf16x8;

#define VMCNT8() asm volatile("s_waitcnt vmcnt(8)" ::: "memory")
#define VMCNT4() asm volatile("s_waitcnt vmcnt(4)" ::: "memory")
#define VMCNT0() asm volatile("s_waitcnt vmcnt(0)" ::: "memory")

__device__ __forceinline__ unsigned short f2bf(float v) {
    unsigned int u = __float_as_uint(v);
    u += 0x7FFFu + ((u >> 16) & 1u);   // RNE to bf16
    return (unsigned short)(u >> 16);
}
__device__ __forceinline__ float bf2f(unsigned short h) {
    return __uint_as_float(((unsigned int)h) << 16);
}
__device__ __forceinline__ unsigned short f2h_bits(float v) {
    return __half_as_ushort(__float2half(v));
}
__device__ __forceinline__ float h2f_bits(unsigned short b) {
    return __half2float(__ushort_as_half(b));
}
__device__ __forceinline__ void async16(const void* g, void* l) {
    __builtin_amdgcn_global_load_lds(
        (const __attribute__((address_space(1))) unsigned int*)g,
        (__attribute__((address_space(3))) unsigned int*)l, 16, 0, 0);
}

// ---------------------------------------------------------------- K0: converts
__global__ __launch_bounds__(256) void k0_prep_x(
    const float* __restrict__ x, const float* __restrict__ b_dec,
    unsigned short* __restrict__ xbf)
{
    const int i = blockIdx.x * 256 + threadIdx.x;      // over 1,572,864 float4s
    const float4 v = reinterpret_cast<const float4*>(x)[i];
    const float4 bd = reinterpret_cast<const float4*>(b_dec)[i % (DD / 4)];
    ushort4 h;
    h.x = f2bf(v.x - bd.x); h.y = f2bf(v.y - bd.y);
    h.z = f2bf(v.z - bd.z); h.w = f2bf(v.w - bd.w);
    reinterpret_cast<ushort4*>(xbf)[i] = h;
}

__global__ __launch_bounds__(256) void k0_cvt_bf(
    const float* __restrict__ src, unsigned short* __restrict__ dst)
{
    const int i = blockIdx.x * 256 + threadIdx.x;
    const float4 v = reinterpret_cast<const float4*>(src)[i];
    ushort4 h;
    h.x = f2bf(v.x); h.y = f2bf(v.y); h.z = f2bf(v.z); h.w = f2bf(v.w);
    reinterpret_cast<ushort4*>(dst)[i] = h;
}

// ---------------------------------------------------------------- K1a: gate
__global__ __launch_bounds__(256) void k1_gate(
    const float* __restrict__ x, const float* __restrict__ gate_W,
    const float* __restrict__ gate_b, const float* __restrict__ b_gate,
    int* __restrict__ eids, double* __restrict__ entw,
    int* __restrict__ rnk, int* __restrict__ blk_cnt)
{
    __shared__ int cnt[NE];
    const int wid  = threadIdx.x >> 6;
    const int lane = threadIdx.x & 63;
    const int blk  = blockIdx.x;
    const int tok  = blk * 4 + wid;

    if (threadIdx.x < NE) cnt[threadIdx.x] = 0;
    __syncthreads();

    double xv[12];
#pragma unroll
    for (int j = 0; j < 12; ++j) {
        const int k = j * 64 + lane;
        xv[j] = (double)x[(size_t)tok * DD + k] - (double)b_gate[k];
    }

    double myLogit = -1.0e300;
    for (int e = 0; e < NE; ++e) {
        double d = 0.0;
#pragma unroll
        for (int j = 0; j < 12; ++j)
            d += xv[j] * (double)gate_W[e * DD + j * 64 + lane];
#pragma unroll
        for (int off = 32; off > 0; off >>= 1)
            d += __shfl_xor(d, off);
        if (lane == e) myLogit = d + (double)gate_b[e];
    }

    double m = myLogit;
#pragma unroll
    for (int off = 8; off > 0; off >>= 1) {
        double o = __shfl_xor(m, off); m = (o > m) ? o : m;
    }
    double p = exp(myLogit - m);
    double ssum = p;
#pragma unroll
    for (int off = 8; off > 0; off >>= 1) ssum += __shfl_xor(ssum, off);
    const double score = p / ssum;

    const bool lt16 = (lane < NE);
    double m1 = score;
#pragma unroll
    for (int off = 8; off > 0; off >>= 1) {
        double o = __shfl_xor(m1, off); m1 = (o > m1) ? o : m1;
    }
    unsigned long long b0 = __ballot(lt16 && (score == m1));
    const int i0 = __ffsll(b0) - 1;
    double sc2 = (lane == i0) ? -1.0 : score;
    double m2 = sc2;
#pragma unroll
    for (int off = 8; off > 0; off >>= 1) {
        double o = __shfl_xor(m2, off); m2 = (o > m2) ? o : m2;
    }
    unsigned long long b1 = __ballot(lt16 && (sc2 == m2));
    const int i1 = __ffsll(b1) - 1;

    if (lane == 0) {
        const double w0 = 1.0 / (1.0 + exp(m2 - m1));
        const double w1 = 1.0 - w0;
        eids[tok * 2 + 0] = i0;
        eids[tok * 2 + 1] = i1;
        entw[tok * 2 + 0] = w0;
        entw[tok * 2 + 1] = w1;
        rnk[tok * 2 + 0] = atomicAdd(&cnt[i0], 1);
        rnk[tok * 2 + 1] = atomicAdd(&cnt[i1], 1);
    }
    __syncthreads();
    if (threadIdx.x < NE) blk_cnt[threadIdx.x * K1BLK + blk] = cnt[threadIdx.x];
}

// ---------------------------------------------------------------- K1b: scan
__global__ __launch_bounds__(256) void k1_scan(
    const int* __restrict__ blk_cnt, int* __restrict__ blk_off,
    int* __restrict__ counts)
{
    __shared__ int tsum[256];
    const int t = threadIdx.x;
    for (int e = 0; e < NE; ++e) {
        int loc[8]; int s = 0;
#pragma unroll
        for (int i = 0; i < 8; ++i) { loc[i] = s; s += blk_cnt[e * K1BLK + t * 8 + i]; }
        tsum[t] = s;
        __syncthreads();
        for (int off = 1; off < 256; off <<= 1) {
            const int u = (t >= off) ? tsum[t - off] : 0;
            __syncthreads();
            tsum[t] += u;
            __syncthreads();
        }
        const int excl = tsum[t] - s;
#pragma unroll
        for (int i = 0; i < 8; ++i) blk_off[e * K1BLK + t * 8 + i] = excl + loc[i];
        if (t == 255) counts[e] = tsum[255];
        __syncthreads();
    }
}

// ---------------------------------------------------------------- K1c: scatter
__global__ __launch_bounds__(256) void k1_scatter(
    const int* __restrict__ eids, const int* __restrict__ rnk,
    const int* __restrict__ blk_off, int* __restrict__ lists)
{
    const int i = blockIdx.x * 256 + threadIdx.x;   // 16384 entries
    const int e = eids[i];
    const int blk = i >> 3;
    lists[e * MAXT + blk_off[e * K1BLK + blk] + rnk[i]] = i;
}

// ------------------------------------------------- K2: grouped expert GEMM
// pure-bf16, double-buffered LDS, all-async staging, counted vmcnt (T3+T4).
template<bool WBF>
__global__ __launch_bounds__(256, 2) void k2_encode(
    const unsigned short* __restrict__ xbf,
    const unsigned short* __restrict__ wbf,
    const float* __restrict__ expert_W,
    const float* __restrict__ expert_b,
    const int* __restrict__ counts, const int* __restrict__ lists,
    const double* __restrict__ entw, unsigned short* __restrict__ fbuf)
{
    const int e = blockIdx.z;
    const int cnt = counts[e];
    const int mbase = blockIdx.y * 128;
    if (mbase >= cnt) return;
    const int rows = min(128, cnt - mbase);
    const int nbase = blockIdx.x * 128;

    __shared__ char smem[65536];   // 2 buffers x (A 16KB | B 16KB)

    const int t = threadIdx.x;
    const int lane = t & 63;
    const int wid = t >> 6;
    const int wm = wid >> 1, wn = wid & 1;
    const int l15 = lane & 15, q = lane >> 4;
    const int rl = lane >> 3;          // row-within-8 for async staging
    const int cg = lane & 7;           // 16B chunk index
    const int xorc = (cg ^ rl) << 4;   // inverse-swizzled source chunk byte

    size_t asrc[4];
#pragma unroll
    for (int j = 0; j < 4; ++j) {
        const int r = (wid * 4 + j) * 8 + rl;
        const int rr = (r < rows) ? r : 0;
        const int tok = lists[e * MAXT + mbase + rr] >> 1;
        asrc[j] = (size_t)tok * (DD * 2) + xorc;
    }
    size_t bsrc[4];
#pragma unroll
    for (int j = 0; j < 4; ++j) {
        const int r = (wid * 4 + j) * 8 + rl;
        bsrc[j] = ((size_t)(e * EDD + nbase + r)) * (DD * 2) + xorc;
    }
    const int kq = t & 15, rg = t >> 4;   // !WBF B-convert map

    f32x4 acc[4][4];
#pragma unroll
    for (int a = 0; a < 4; ++a)
#pragma unroll
        for (int b = 0; b < 4; ++b)
            acc[a][b] = f32x4{0.f, 0.f, 0.f, 0.f};

    auto stageA = [&](int s, char* buf) {
#pragma unroll
        for (int j = 0; j < 4; ++j)
            async16((const char*)xbf + asrc[j] + (size_t)s * BKBYTES,
                    buf + ((wid * 4 + j) << 10));
    };
    auto stageB_async = [&](int s, char* buf) {
#pragma unroll
        for (int j = 0; j < 4; ++j)
            async16((const char*)wbf + bsrc[j] + (size_t)s * BKBYTES,
                    buf + 16384 + ((wid * 4 + j) << 10));
    };
    auto stageB_cvt = [&](int s, char* buf) {
#pragma unroll
        for (int j = 0; j < 8; ++j) {
            const int r = rg * 8 + j;
            const float4 bv = *reinterpret_cast<const float4*>(
                expert_W + ((size_t)e * EDD + nbase + r) * DD + s * 64 + kq * 4);
            ushort4 b4;
            b4.x = f2bf(bv.x); b4.y = f2bf(bv.y); b4.z = f2bf(bv.z); b4.w = f2bf(bv.w);
            *reinterpret_cast<ushort4*>(
                buf + 16384 + ((r * 128 + kq * 8) ^ ((r & 7) << 4))) = b4;
        }
    };
    auto compute = [&](char* buf) {
#pragma unroll
        for (int ks = 0; ks < 2; ++ks) {
            bf16x8 ah[4], bh[4];
#pragma unroll
            for (int fm = 0; fm < 4; ++fm) {
                const int row = wm * 64 + fm * 16 + l15;
                ah[fm] = *reinterpret_cast<const bf16x8*>(
                    buf + row * 128 + ((ks * 64 + q * 16) ^ ((row & 7) << 4)));
            }
#pragma unroll
            for (int fn = 0; fn < 4; ++fn) {
                const int row = wn * 64 + fn * 16 + l15;
                bh[fn] = *reinterpret_cast<const bf16x8*>(
                    buf + 16384 + row * 128 + ((ks * 64 + q * 16) ^ ((row & 7) << 4)));
            }
#pragma unroll
            for (int fm = 0; fm < 4; ++fm)
#pragma unroll
                for (int fn = 0; fn < 4; ++fn)
                    acc[fm][fn] = __builtin_amdgcn_mfma_f32_16x16x32_bf16(
                        ah[fm], bh[fn], acc[fm][fn], 0, 0, 0);
        }
    };

    // prologue: stage tile 0 into buffer 0
    if constexpr (WBF) {
        stageA(0, smem);
        stageB_async(0, smem);
    } else {
        stageB_cvt(0, smem);
        stageA(0, smem);
    }

    for (int s = 0; s < NSTEP; ++s) {
        char* cur = smem + ((s & 1) << 15);
        char* nxt = smem + (((s & 1) ^ 1) << 15);
        if (s + 1 < NSTEP) {
            if constexpr (WBF) {
                stageA(s + 1, nxt);
                stageB_async(s + 1, nxt);
                VMCNT8();              // retire tile s, keep tile s+1 in flight
            } else {
                stageB_cvt(s + 1, nxt);
                stageA(s + 1, nxt);
                VMCNT4();
            }
        } else {
            VMCNT0();
        }
        __syncthreads();
        compute(cur);
        __syncthreads();
    }

    // epilogue: C/D layout col=lane&15, row=(lane>>4)*4+reg; bias+relu+renorm; f16 out
#pragma unroll
    for (int fm = 0; fm < 4; ++fm) {
#pragma unroll
        for (int r = 0; r < 4; ++r) {
            const int ml = wm * 64 + fm * 16 + q * 4 + r;
            if (ml >= rows) continue;
            const int ent = lists[e * MAXT + mbase + ml];
            const float ren = (float)entw[ent];
            unsigned short* fout = fbuf + (size_t)ent * EDD + nbase;
#pragma unroll
            for (int fn = 0; fn < 4; ++fn) {
                const int nl = wn * 64 + fn * 16 + l15;
                float v = acc[fm][fn][r] + expert_b[e * EDD + nbase + nl];
                v = fmaxf(v, 0.f) * ren;
                fout[nl] = f2h_bits(v);
            }
        }
    }
}

// --------------------------- K3: per-token exact top-100 + fused decode
// f16-stored f; 2-pass radix; conf >= T+41 ulp; candidates in +-40 ulp
// re-evaluated in fp64; parallel rank-based final selection.
template<int DEC16>
__global__ __launch_bounds__(256) void k3_topk_decode(
    const float* __restrict__ x, const float* __restrict__ b_dec,
    const float* __restrict__ expert_W, const float* __restrict__ expert_b,
    const int* __restrict__ eids, const double* __restrict__ entw,
    const unsigned short* __restrict__ fbuf,
    const float* __restrict__ decoder, const unsigned short* __restrict__ dec16,
    float* __restrict__ out)
{
    const int tok = blockIdx.x;
    const int t = threadIdx.x;

    __shared__ unsigned short fv[3072];
    __shared__ unsigned int hist[256];
    __shared__ int hb_s, T_s, rem_s, tz_s, nsel_s, ncand_s, total_s, need_s;
    __shared__ int   sel_didx[KTOP];
    __shared__ float sel_act[KTOP];
    __shared__ int    cidx[CAND_MAX];
    __shared__ double cval[CAND_MAX];

    const unsigned int* frow = reinterpret_cast<const unsigned int*>(fbuf + (size_t)tok * 2 * EDD);
#pragma unroll
    for (int i = 0; i < 6; ++i)
        reinterpret_cast<unsigned int*>(fv)[t + 256 * i] = frow[t + 256 * i];
    if (t == 0) { tz_s = 0; nsel_s = 0; ncand_s = 0; }
    hist[t] = 0u;
    __syncthreads();

    // pass 1: top byte of f16 bits (all values >= 0)
#pragma unroll
    for (int i = 0; i < 12; ++i) {
        const unsigned int u = fv[t + 256 * i];
        if (u) atomicAdd(&hist[u >> 8], 1u);
    }
    __syncthreads();
    if (t == 0) {
        unsigned int cum = 0; int v = 255;
        for (; v >= 0; --v) { const unsigned int c = hist[v]; if (cum + c >= KTOP) break; cum += c; }
        if (v < 0) tz_s = 1;
        else { hb_s = v; rem_s = KTOP - (int)cum; }
    }
    __syncthreads();

    if (!tz_s) {
        hist[t] = 0u;
        __syncthreads();
        const unsigned int hb = (unsigned int)hb_s;
#pragma unroll
        for (int i = 0; i < 12; ++i) {
            const unsigned int u = fv[t + 256 * i];
            if (u && (u >> 8) == hb) atomicAdd(&hist[u & 255u], 1u);
        }
        __syncthreads();
        if (t == 0) {
            const int rem = rem_s; unsigned int cum = 0; int v = 255;
            for (; v >= 0; --v) { const unsigned int c = hist[v]; if (cum + c >= (unsigned int)rem) break; cum += c; }
            T_s = (hb_s << 8) | v;
        }
        __syncthreads();
    }

    if (tz_s) {
        // fewer than 100 positives: take them all (rest are exact zeros)
#pragma unroll
        for (int i = 0; i < 12; ++i) {
            const int j = t + 256 * i;
            const unsigned int u = fv[j];
            if (u) {
                const int p = atomicAdd(&nsel_s, 1);
                const int slot = (j >= EDD) ? 1 : 0;
                const int n = j - slot * EDD;
                sel_didx[p] = eids[tok * 2 + slot] * EDD + n;
                sel_act[p] = h2f_bits((unsigned short)u);
            }
        }
        __syncthreads();
        if (t == 0) total_s = nsel_s;
        __syncthreads();
    } else {
        const int T = T_s;
#pragma unroll
        for (int i = 0; i < 12; ++i) {
            const int j = t + 256 * i;
            const unsigned int u = fv[j];
            if ((int)u >= T + CONF_ULP) {
                const int p = atomicAdd(&nsel_s, 1);
                const int slot = (j >= EDD) ? 1 : 0;
                const int n = j - slot * EDD;
                sel_didx[p] = eids[tok * 2 + slot] * EDD + n;
                sel_act[p] = h2f_bits((unsigned short)u);
            } else if (u != 0u && (int)u + BAND_ULP >= T) {
                const int c = atomicAdd(&ncand_s, 1);
                if (c < CAND_MAX) cidx[c] = j;
            }
        }
        __syncthreads();

        // fp64 re-evaluation of candidates, one wave per candidate
        {
            const int ncand = min(ncand_s, CAND_MAX);
            const int wv = t >> 6, lane = t & 63;
            for (int c = wv; c < ncand; c += 4) {
                const int j = cidx[c];
                const int slot = (j >= EDD) ? 1 : 0;
                const int n = j - slot * EDD;
                const int ee = eids[tok * 2 + slot];
                const float* wr = expert_W + ((size_t)ee * EDD + n) * DD;
                const float* xr = x + (size_t)tok * DD;
                double d = 0.0;
#pragma unroll
                for (int jj = 0; jj < 12; ++jj) {
                    const int k = jj * 64 + lane;
                    d += ((double)xr[k] - (double)b_dec[k]) * (double)wr[k];
                }
#pragma unroll
                for (int off = 32; off > 0; off >>= 1) d += __shfl_xor(d, off);
                if (lane == 0) {
                    double z = d + (double)expert_b[ee * EDD + n];
                    if (z < 0.0) z = 0.0;
                    cval[c] = z * entw[tok * 2 + slot];
                }
            }
        }
        __syncthreads();
        if (t == 0) {
            const int ncand = min(ncand_s, CAND_MAX);
            int need = KTOP - nsel_s;
            if (need > ncand) need = ncand;
            if (need < 0) need = 0;
            need_s = need;
            total_s = nsel_s + need;
        }
        __syncthreads();

        // parallel rank-based selection among candidates (value desc, dict idx asc)
        {
            const int ncand = min(ncand_s, CAND_MAX);
            if (t < ncand) {
                const int j = cidx[t];
                const int slot = (j >= EDD) ? 1 : 0;
                const int my_didx = eids[tok * 2 + slot] * EDD + (j - slot * EDD);
                const double v = cval[t];
                int rank = 0;
                for (int i = 0; i < ncand; ++i) {
                    const int ji = cidx[i];
                    const int si = (ji >= EDD) ? 1 : 0;
                    const int di = eids[tok * 2 + si] * EDD + (ji - si * EDD);
                    const double vi = cval[i];
                    rank += (vi > v) || (vi == v && di < my_didx);
                }
                if (rank < need_s) {
                    sel_didx[nsel_s + rank] = my_didx;
                    sel_act[nsel_s + rank] = (float)v;
                }
            }
        }
        __syncthreads();
    }

    // fused decode: x_hat = sum a_k * decoder[idx_k] + b_dec
    const int total = total_s;
    float a0 = 0.f, a1 = 0.f, a2 = 0.f;
    for (int k = 0; k < total; ++k) {
        const float a = sel_act[k];
        if (DEC16) {
            const unsigned short* dr = dec16 + (size_t)sel_didx[k] * DD;
            a0 += a * bf2f(dr[t]);
            a1 += a * bf2f(dr[t + 256]);
            a2 += a * bf2f(dr[t + 512]);
        } else {
            const float* dr = decoder + (size_t)sel_didx[k] * DD;
            a0 += a * dr[t];
            a1 += a * dr[t + 256];
            a2 += a * dr[t + 512];
        }
    }
    out[(size_t)tok * DD + t]       = a0 + b_dec[t];
    out[(size_t)tok * DD + t + 256] = a1 + b_dec[t + 256];
    out[(size_t)tok * DD + t + 512] = a2 + b_dec[t + 512];
}

// sentinel fill if workspace is too small (diagnosable: absmax ~ 12345)
__global__ void k_sentinel(float* __restrict__ out, int n) {
    int i = blockIdx.x * blockDim.x + threadIdx.x;
    if (i < n) out[i] = 12345.0f;
}

extern "C" void kernel_launch(void* const* d_in, const int* in_sizes, int n_in,
                              void* d_out, int out_size, void* d_ws, size_t ws_size,
                              hipStream_t stream)
{
    (void)in_sizes; (void)n_in;
    const float* x        = (const float*)d_in[0];
    const float* gate_W   = (const float*)d_in[1];
    const float* gate_b   = (const float*)d_in[2];
    const float* b_gate   = (const float*)d_in[3];
    const float* b_dec    = (const float*)d_in[4];
    const float* expert_W = (const float*)d_in[5];
    const float* expert_b = (const float*)d_in[6];
    const float* decoder  = (const float*)d_in[7];
    float* out = (float*)d_out;

    char* ws = (char*)d_ws;
    const size_t off_blkcnt = 256;
    const size_t off_blkoff = off_blkcnt + (size_t)NE * K1BLK * 4;
    const size_t off_rnk    = off_blkoff + (size_t)NE * K1BLK * 4;
    const size_t off_eids   = off_rnk    + (size_t)NB * 2 * 4;
    const size_t off_entw   = off_eids   + (size_t)NB * 2 * 4;
    const size_t off_lists  = off_entw   + (size_t)NB * 2 * 8;
    const size_t off_fbuf   = off_lists  + (size_t)NE * MAXT * 4;
    const size_t off_xbf    = off_fbuf   + (size_t)NB * 2 * EDD * 2;
    const size_t base_end   = off_xbf    + (size_t)NB * DD * 2;      // ~64.0 MB
    const size_t WSZ        = (size_t)NE * EDD * DD * 2;             // 37.75 MB

    if (ws_size < base_end) {
        k_sentinel<<<(out_size + 255) / 256, 256, 0, stream>>>(out, out_size);
        return;
    }
    size_t off = base_end;
    const bool have_w = (ws_size >= off + WSZ);
    unsigned short* wbf = have_w ? (unsigned short*)(ws + off) : nullptr;
    if (have_w) off += WSZ;
    const bool have_d = (ws_size >= off + WSZ);
    unsigned short* dec16v = have_d ? (unsigned short*)(ws + off) : nullptr;

    int*            counts  = (int*)ws;
    int*            blk_cnt = (int*)(ws + off_blkcnt);
    int*            blk_off = (int*)(ws + off_blkoff);
    int*            rnk     = (int*)(ws + off_rnk);
    int*            eids    = (int*)(ws + off_eids);
    double*         entw    = (double*)(ws + off_entw);
    int*            lists   = (int*)(ws + off_lists);
    unsigned short* fbuf    = (unsigned short*)(ws + off_fbuf);
    unsigned short* xbf     = (unsigned short*)(ws + off_xbf);

    hipMemsetAsync(counts, 0, 64, stream);

    k0_prep_x<<<(NB * DD / 4) / 256, 256, 0, stream>>>(x, b_dec, xbf);
    const int n4blocks = (NE * EDD * DD / 4) / 256;   // 18432
    if (have_w)
        k0_cvt_bf<<<n4blocks, 256, 0, stream>>>(expert_W, wbf);
    if (have_d)
        k0_cvt_bf<<<n4blocks, 256, 0, stream>>>(decoder, dec16v);

    k1_gate<<<K1BLK, 256, 0, stream>>>(x, gate_W, gate_b, b_gate, eids, entw, rnk, blk_cnt);
    k1_scan<<<1, 256, 0, stream>>>(blk_cnt, blk_off, counts);
    k1_scatter<<<NB * 2 / 256, 256, 0, stream>>>(eids, rnk, blk_off, lists);

    dim3 g2(EDD / 128, MAXT / 128, NE);   // (ntile=12, mtile=64, e=16), early-exit
    if (have_w)
        k2_encode<true><<<g2, 256, 0, stream>>>(xbf, wbf, expert_W, expert_b,
                                                counts, lists, entw, fbuf);
    else
        k2_encode<false><<<g2, 256, 0, stream>>>(xbf, wbf, expert_W, expert_b,
                                                 counts, lists, entw, fbuf);

    if (have_d)
        k3_topk_decode<1><<<NB, 256, 0, stream>>>(x, b_dec, expert_W, expert_b, eids,
                                                  entw, fbuf, decoder, dec16v, out);
    else
        k3_topk_decode<0><<<NB, 256, 0, stream>>>(x, b_dec, expert_W, expert_b, eids,
                                                  entw, fbuf, decoder, dec16v, out);
}

// Round 4
// 427.417 us; speedup vs baseline: 2.6392x; 1.1526x over previous
//
#include <hip/hip_runtime.h>
#include <hip/hip_fp16.h>
#include <cstdint>
#include <cstddef>

#define NB    8192
#define DD    768
#define NE    16
#define EDD   1536
#define KTOP  100
#define MAXT  8192
#define CAND_MAX 256
#define K1BLK 2048
#define NSTEP 12
#define BKBYTES 128      // 64 k * 2B
#define CONF_ULP 21
#define BAND_ULP 20

typedef __attribute__((ext_vector_type(4))) float f32x4;
typedef __attribute__((ext_vector_type(8))) short bf16x8;

#define VMCNT8() asm volatile("s_waitcnt vmcnt(8)" ::: "memory")
#define VMCNT4() asm volatile("s_waitcnt vmcnt(4)" ::: "memory")
#define VMCNT0() asm volatile("s_waitcnt vmcnt(0)" ::: "memory")

__device__ __forceinline__ unsigned short f2bf(float v) {
    unsigned int u = __float_as_uint(v);
    u += 0x7FFFu + ((u >> 16) & 1u);   // RNE to bf16
    return (unsigned short)(u >> 16);
}
__device__ __forceinline__ float bf2f(unsigned short h) {
    return __uint_as_float(((unsigned int)h) << 16);
}
__device__ __forceinline__ unsigned short f2h_bits(float v) {
    return __half_as_ushort(__float2half(v));
}
__device__ __forceinline__ float h2f_bits(unsigned short b) {
    return __half2float(__ushort_as_half(b));
}
__device__ __forceinline__ void async16(const void* g, void* l) {
    __builtin_amdgcn_global_load_lds(
        (const __attribute__((address_space(1))) unsigned int*)g,
        (__attribute__((address_space(3))) unsigned int*)l, 16, 0, 0);
}

// ---------------------------------------------------------------- K0: converts
__global__ __launch_bounds__(256) void k0_prep_x(
    const float* __restrict__ x, const float* __restrict__ b_dec,
    unsigned short* __restrict__ xbf)
{
    const int i = blockIdx.x * 256 + threadIdx.x;      // over 1,572,864 float4s
    const float4 v = reinterpret_cast<const float4*>(x)[i];
    const float4 bd = reinterpret_cast<const float4*>(b_dec)[i % (DD / 4)];
    ushort4 h;
    h.x = f2bf(v.x - bd.x); h.y = f2bf(v.y - bd.y);
    h.z = f2bf(v.z - bd.z); h.w = f2bf(v.w - bd.w);
    reinterpret_cast<ushort4*>(xbf)[i] = h;
}

__global__ __launch_bounds__(256) void k0_cvt_bf(
    const float* __restrict__ src, unsigned short* __restrict__ dst)
{
    const int i = blockIdx.x * 256 + threadIdx.x;
    const float4 v = reinterpret_cast<const float4*>(src)[i];
    ushort4 h;
    h.x = f2bf(v.x); h.y = f2bf(v.y); h.z = f2bf(v.z); h.w = f2bf(v.w);
    reinterpret_cast<ushort4*>(dst)[i] = h;
}

// ---------------------------------------------------------------- K1a: gate
__global__ __launch_bounds__(256) void k1_gate(
    const float* __restrict__ x, const float* __restrict__ gate_W,
    const float* __restrict__ gate_b, const float* __restrict__ b_gate,
    int* __restrict__ eids, double* __restrict__ entw,
    int* __restrict__ rnk, int* __restrict__ blk_cnt)
{
    __shared__ int cnt[NE];
    const int wid  = threadIdx.x >> 6;
    const int lane = threadIdx.x & 63;
    const int blk  = blockIdx.x;
    const int tok  = blk * 4 + wid;

    if (threadIdx.x < NE) cnt[threadIdx.x] = 0;
    __syncthreads();

    double xv[12];
#pragma unroll
    for (int j = 0; j < 12; ++j) {
        const int k = j * 64 + lane;
        xv[j] = (double)x[(size_t)tok * DD + k] - (double)b_gate[k];
    }

    double myLogit = -1.0e300;
    for (int e = 0; e < NE; ++e) {
        double d = 0.0;
#pragma unroll
        for (int j = 0; j < 12; ++j)
            d += xv[j] * (double)gate_W[e * DD + j * 64 + lane];
#pragma unroll
        for (int off = 32; off > 0; off >>= 1)
            d += __shfl_xor(d, off);
        if (lane == e) myLogit = d + (double)gate_b[e];
    }

    double m = myLogit;
#pragma unroll
    for (int off = 8; off > 0; off >>= 1) {
        double o = __shfl_xor(m, off); m = (o > m) ? o : m;
    }
    double p = exp(myLogit - m);
    double ssum = p;
#pragma unroll
    for (int off = 8; off > 0; off >>= 1) ssum += __shfl_xor(ssum, off);
    const double score = p / ssum;

    const bool lt16 = (lane < NE);
    double m1 = score;
#pragma unroll
    for (int off = 8; off > 0; off >>= 1) {
        double o = __shfl_xor(m1, off); m1 = (o > m1) ? o : m1;
    }
    unsigned long long b0 = __ballot(lt16 && (score == m1));
    const int i0 = __ffsll(b0) - 1;
    double sc2 = (lane == i0) ? -1.0 : score;
    double m2 = sc2;
#pragma unroll
    for (int off = 8; off > 0; off >>= 1) {
        double o = __shfl_xor(m2, off); m2 = (o > m2) ? o : m2;
    }
    unsigned long long b1 = __ballot(lt16 && (sc2 == m2));
    const int i1 = __ffsll(b1) - 1;

    if (lane == 0) {
        const double w0 = 1.0 / (1.0 + exp(m2 - m1));
        const double w1 = 1.0 - w0;
        eids[tok * 2 + 0] = i0;
        eids[tok * 2 + 1] = i1;
        entw[tok * 2 + 0] = w0;
        entw[tok * 2 + 1] = w1;
        rnk[tok * 2 + 0] = atomicAdd(&cnt[i0], 1);
        rnk[tok * 2 + 1] = atomicAdd(&cnt[i1], 1);
    }
    __syncthreads();
    if (threadIdx.x < NE) blk_cnt[threadIdx.x * K1BLK + blk] = cnt[threadIdx.x];
}

// ---------------------------------------------------------------- K1b: scan (one block per expert)
__global__ __launch_bounds__(256) void k1_scan(
    const int* __restrict__ blk_cnt, int* __restrict__ blk_off,
    int* __restrict__ counts)
{
    __shared__ int tsum[256];
    const int e = blockIdx.x;
    const int t = threadIdx.x;
    int loc[8]; int s = 0;
#pragma unroll
    for (int i = 0; i < 8; ++i) { loc[i] = s; s += blk_cnt[e * K1BLK + t * 8 + i]; }
    tsum[t] = s;
    __syncthreads();
    for (int off = 1; off < 256; off <<= 1) {
        const int u = (t >= off) ? tsum[t - off] : 0;
        __syncthreads();
        tsum[t] += u;
        __syncthreads();
    }
    const int excl = tsum[t] - s;
#pragma unroll
    for (int i = 0; i < 8; ++i) blk_off[e * K1BLK + t * 8 + i] = excl + loc[i];
    if (t == 255) counts[e] = tsum[255];
}

// ---------------------------------------------------------------- K1c: scatter
__global__ __launch_bounds__(256) void k1_scatter(
    const int* __restrict__ eids, const int* __restrict__ rnk,
    const int* __restrict__ blk_off, int* __restrict__ lists)
{
    const int i = blockIdx.x * 256 + threadIdx.x;   // 16384 entries
    const int e = eids[i];
    const int blk = i >> 3;
    lists[e * MAXT + blk_off[e * K1BLK + blk] + rnk[i]] = i;
}

// ------------------------------------------------- K2: grouped expert GEMM
// pure-bf16, double-buffered LDS, all-async staging, counted vmcnt (T3+T4).
template<bool WBF>
__global__ __launch_bounds__(256, 2) void k2_encode(
    const unsigned short* __restrict__ xbf,
    const unsigned short* __restrict__ wbf,
    const float* __restrict__ expert_W,
    const float* __restrict__ expert_b,
    const int* __restrict__ counts, const int* __restrict__ lists,
    const double* __restrict__ entw, unsigned short* __restrict__ fbuf)
{
    const int e = blockIdx.z;
    const int cnt = counts[e];
    const int mbase = blockIdx.y * 128;
    if (mbase >= cnt) return;
    const int rows = min(128, cnt - mbase);
    const int nbase = blockIdx.x * 128;

    __shared__ char smem[65536];   // 2 buffers x (A 16KB | B 16KB)

    const int t = threadIdx.x;
    const int lane = t & 63;
    const int wid = t >> 6;
    const int wm = wid >> 1, wn = wid & 1;
    const int l15 = lane & 15, q = lane >> 4;
    const int rl = lane >> 3;          // row-within-8 for async staging
    const int cg = lane & 7;           // 16B chunk index
    const int xorc = (cg ^ rl) << 4;   // inverse-swizzled source chunk byte

    size_t asrc[4];
#pragma unroll
    for (int j = 0; j < 4; ++j) {
        const int r = (wid * 4 + j) * 8 + rl;
        const int rr = (r < rows) ? r : 0;
        const int tok = lists[e * MAXT + mbase + rr] >> 1;
        asrc[j] = (size_t)tok * (DD * 2) + xorc;
    }
    size_t bsrc[4];
#pragma unroll
    for (int j = 0; j < 4; ++j) {
        const int r = (wid * 4 + j) * 8 + rl;
        bsrc[j] = ((size_t)(e * EDD + nbase + r)) * (DD * 2) + xorc;
    }
    const int kq = t & 15, rg = t >> 4;   // !WBF B-convert map

    f32x4 acc[4][4];
#pragma unroll
    for (int a = 0; a < 4; ++a)
#pragma unroll
        for (int b = 0; b < 4; ++b)
            acc[a][b] = f32x4{0.f, 0.f, 0.f, 0.f};

    auto stageA = [&](int s, char* buf) {
#pragma unroll
        for (int j = 0; j < 4; ++j)
            async16((const char*)xbf + asrc[j] + (size_t)s * BKBYTES,
                    buf + ((wid * 4 + j) << 10));
    };
    auto stageB_async = [&](int s, char* buf) {
#pragma unroll
        for (int j = 0; j < 4; ++j)
            async16((const char*)wbf + bsrc[j] + (size_t)s * BKBYTES,
                    buf + 16384 + ((wid * 4 + j) << 10));
    };
    auto stageB_cvt = [&](int s, char* buf) {
#pragma unroll
        for (int j = 0; j < 8; ++j) {
            const int r = rg * 8 + j;
            const float4 bv = *reinterpret_cast<const float4*>(
                expert_W + ((size_t)e * EDD + nbase + r) * DD + s * 64 + kq * 4);
            ushort4 b4;
            b4.x = f2bf(bv.x); b4.y = f2bf(bv.y); b4.z = f2bf(bv.z); b4.w = f2bf(bv.w);
            *reinterpret_cast<ushort4*>(
                buf + 16384 + ((r * 128 + kq * 8) ^ ((r & 7) << 4))) = b4;
        }
    };
    auto compute = [&](char* buf) {
#pragma unroll
        for (int ks = 0; ks < 2; ++ks) {
            bf16x8 ah[4], bh[4];
#pragma unroll
            for (int fm = 0; fm < 4; ++fm) {
                const int row = wm * 64 + fm * 16 + l15;
                ah[fm] = *reinterpret_cast<const bf16x8*>(
                    buf + row * 128 + ((ks * 64 + q * 16) ^ ((row & 7) << 4)));
            }
#pragma unroll
            for (int fn = 0; fn < 4; ++fn) {
                const int row = wn * 64 + fn * 16 + l15;
                bh[fn] = *reinterpret_cast<const bf16x8*>(
                    buf + 16384 + row * 128 + ((ks * 64 + q * 16) ^ ((row & 7) << 4)));
            }
#pragma unroll
            for (int fm = 0; fm < 4; ++fm)
#pragma unroll
                for (int fn = 0; fn < 4; ++fn)
                    acc[fm][fn] = __builtin_amdgcn_mfma_f32_16x16x32_bf16(
                        ah[fm], bh[fn], acc[fm][fn], 0, 0, 0);
        }
    };

    // prologue: stage tile 0 into buffer 0
    if constexpr (WBF) {
        stageA(0, smem);
        stageB_async(0, smem);
    } else {
        stageB_cvt(0, smem);
        stageA(0, smem);
    }

    for (int s = 0; s < NSTEP; ++s) {
        char* cur = smem + ((s & 1) << 15);
        char* nxt = smem + (((s & 1) ^ 1) << 15);
        if (s + 1 < NSTEP) {
            if constexpr (WBF) {
                stageA(s + 1, nxt);
                stageB_async(s + 1, nxt);
                VMCNT8();              // retire tile s, keep tile s+1 in flight
            } else {
                stageB_cvt(s + 1, nxt);
                stageA(s + 1, nxt);
                VMCNT4();
            }
        } else {
            VMCNT0();
        }
        __syncthreads();
        compute(cur);
        __syncthreads();
    }

    // epilogue: C/D layout col=lane&15, row=(lane>>4)*4+reg; bias+relu+renorm; f16 out
#pragma unroll
    for (int fm = 0; fm < 4; ++fm) {
#pragma unroll
        for (int r = 0; r < 4; ++r) {
            const int ml = wm * 64 + fm * 16 + q * 4 + r;
            if (ml >= rows) continue;
            const int ent = lists[e * MAXT + mbase + ml];
            const float ren = (float)entw[ent];
            unsigned short* fout = fbuf + (size_t)ent * EDD + nbase;
#pragma unroll
            for (int fn = 0; fn < 4; ++fn) {
                const int nl = wn * 64 + fn * 16 + l15;
                float v = acc[fm][fn][r] + expert_b[e * EDD + nbase + nl];
                v = fmaxf(v, 0.f) * ren;
                fout[nl] = f2h_bits(v);
            }
        }
    }
}

// --------------------------- K3: per-token exact top-100 + fused decode
// f16-stored f; 2-pass radix; conf >= T+21 ulp (~10 sigma); candidates in
// +-20 ulp re-evaluated in fp64; 4-wave k-split decode, 24B/lane gathers.
template<int DEC16>
__global__ __launch_bounds__(256) void k3_topk_decode(
    const float* __restrict__ x, const float* __restrict__ b_dec,
    const float* __restrict__ expert_W, const float* __restrict__ expert_b,
    const int* __restrict__ eids, const double* __restrict__ entw,
    const unsigned short* __restrict__ fbuf,
    const float* __restrict__ decoder, const unsigned short* __restrict__ dec16,
    float* __restrict__ out)
{
    const int tok = blockIdx.x;
    const int t = threadIdx.x;

    // arena overlay: [fv 6144 | hist 1024 | cidx 1024 | cval 2048] before decode;
    // red[4*768 floats = 12288] after selection (fv/hist/cidx/cval all dead then).
    __shared__ __align__(16) char arena[12288];
    unsigned short* fv   = (unsigned short*)arena;
    unsigned int*   hist = (unsigned int*)(arena + 6144);
    int*            cidx = (int*)(arena + 7168);
    double*         cval = (double*)(arena + 8192);
    float*          red  = (float*)arena;
    __shared__ int hb_s, T_s, rem_s, tz_s, nsel_s, ncand_s, total_s, need_s;
    __shared__ int   sel_didx[KTOP];
    __shared__ float sel_act[KTOP];

    const unsigned int* frow = reinterpret_cast<const unsigned int*>(fbuf + (size_t)tok * 2 * EDD);
#pragma unroll
    for (int i = 0; i < 6; ++i)
        reinterpret_cast<unsigned int*>(fv)[t + 256 * i] = frow[t + 256 * i];
    if (t == 0) { tz_s = 0; nsel_s = 0; ncand_s = 0; }
    hist[t] = 0u;
    __syncthreads();

    // pass 1: top byte of f16 bits (all values >= 0)
#pragma unroll
    for (int i = 0; i < 12; ++i) {
        const unsigned int u = fv[t + 256 * i];
        if (u) atomicAdd(&hist[u >> 8], 1u);
    }
    __syncthreads();
    if (t == 0) {
        unsigned int cum = 0; int v = 255;
        for (; v >= 0; --v) { const unsigned int c = hist[v]; if (cum + c >= KTOP) break; cum += c; }
        if (v < 0) tz_s = 1;
        else { hb_s = v; rem_s = KTOP - (int)cum; }
    }
    __syncthreads();

    if (!tz_s) {
        hist[t] = 0u;
        __syncthreads();
        const unsigned int hb = (unsigned int)hb_s;
#pragma unroll
        for (int i = 0; i < 12; ++i) {
            const unsigned int u = fv[t + 256 * i];
            if (u && (u >> 8) == hb) atomicAdd(&hist[u & 255u], 1u);
        }
        __syncthreads();
        if (t == 0) {
            const int rem = rem_s; unsigned int cum = 0; int v = 255;
            for (; v >= 0; --v) { const unsigned int c = hist[v]; if (cum + c >= (unsigned int)rem) break; cum += c; }
            T_s = (hb_s << 8) | v;
        }
        __syncthreads();
    }

    if (tz_s) {
        // fewer than 100 positives: take them all (rest are exact zeros)
#pragma unroll
        for (int i = 0; i < 12; ++i) {
            const int j = t + 256 * i;
            const unsigned int u = fv[j];
            if (u) {
                const int p = atomicAdd(&nsel_s, 1);
                const int slot = (j >= EDD) ? 1 : 0;
                const int n = j - slot * EDD;
                sel_didx[p] = eids[tok * 2 + slot] * EDD + n;
                sel_act[p] = h2f_bits((unsigned short)u);
            }
        }
        __syncthreads();
        if (t == 0) total_s = nsel_s;
        __syncthreads();
    } else {
        const int T = T_s;
#pragma unroll
        for (int i = 0; i < 12; ++i) {
            const int j = t + 256 * i;
            const unsigned int u = fv[j];
            if ((int)u >= T + CONF_ULP) {
                const int p = atomicAdd(&nsel_s, 1);
                const int slot = (j >= EDD) ? 1 : 0;
                const int n = j - slot * EDD;
                sel_didx[p] = eids[tok * 2 + slot] * EDD + n;
                sel_act[p] = h2f_bits((unsigned short)u);
            } else if (u != 0u && (int)u + BAND_ULP >= T) {
                const int c = atomicAdd(&ncand_s, 1);
                if (c < CAND_MAX) cidx[c] = j;
            }
        }
        __syncthreads();

        // fp64 re-evaluation of candidates, one wave per candidate
        {
            const int ncand = min(ncand_s, CAND_MAX);
            const int wv = t >> 6, lane = t & 63;
            for (int c = wv; c < ncand; c += 4) {
                const int j = cidx[c];
                const int slot = (j >= EDD) ? 1 : 0;
                const int n = j - slot * EDD;
                const int ee = eids[tok * 2 + slot];
                const float* wr = expert_W + ((size_t)ee * EDD + n) * DD;
                const float* xr = x + (size_t)tok * DD;
                double d = 0.0;
#pragma unroll
                for (int jj = 0; jj < 12; ++jj) {
                    const int k = jj * 64 + lane;
                    d += ((double)xr[k] - (double)b_dec[k]) * (double)wr[k];
                }
#pragma unroll
                for (int off = 32; off > 0; off >>= 1) d += __shfl_xor(d, off);
                if (lane == 0) {
                    double z = d + (double)expert_b[ee * EDD + n];
                    if (z < 0.0) z = 0.0;
                    cval[c] = z * entw[tok * 2 + slot];
                }
            }
        }
        __syncthreads();
        if (t == 0) {
            const int ncand = min(ncand_s, CAND_MAX);
            int need = KTOP - nsel_s;
            if (need > ncand) need = ncand;
            if (need < 0) need = 0;
            need_s = need;
            total_s = nsel_s + need;
        }
        __syncthreads();

        // parallel rank-based selection among candidates (value desc, dict idx asc)
        {
            const int ncand = min(ncand_s, CAND_MAX);
            if (t < ncand) {
                const int j = cidx[t];
                const int slot = (j >= EDD) ? 1 : 0;
                const int my_didx = eids[tok * 2 + slot] * EDD + (j - slot * EDD);
                const double v = cval[t];
                int rank = 0;
                for (int i = 0; i < ncand; ++i) {
                    const int ji = cidx[i];
                    const int si = (ji >= EDD) ? 1 : 0;
                    const int di = eids[tok * 2 + si] * EDD + (ji - si * EDD);
                    const double vi = cval[i];
                    rank += (vi > v) || (vi == v && di < my_didx);
                }
                if (rank < need_s) {
                    sel_didx[nsel_s + rank] = my_didx;
                    sel_act[nsel_s + rank] = (float)v;
                }
            }
        }
        __syncthreads();
    }

    // fused decode: 4-wave k-split; each wave reads full rows at 24B/lane
    // (DEC16) or 48B/lane (fp32), accumulates 12 f32/lane, LDS reduce.
    const int total = total_s;
    const int wv = t >> 6;
    const int lane = t & 63;
    float accd[12];
#pragma unroll
    for (int i = 0; i < 12; ++i) accd[i] = 0.f;

    auto body = [&](int k) {
        const float a = sel_act[k];
        if (DEC16) {
            const char* dr = (const char*)(dec16 + (size_t)sel_didx[k] * DD) + lane * 24;
            const ushort4 u0 = *reinterpret_cast<const ushort4*>(dr);
            const ushort4 u1 = *reinterpret_cast<const ushort4*>(dr + 8);
            const ushort4 u2 = *reinterpret_cast<const ushort4*>(dr + 16);
            accd[0] += a * bf2f(u0.x);  accd[1]  += a * bf2f(u0.y);
            accd[2] += a * bf2f(u0.z);  accd[3]  += a * bf2f(u0.w);
            accd[4] += a * bf2f(u1.x);  accd[5]  += a * bf2f(u1.y);
            accd[6] += a * bf2f(u1.z);  accd[7]  += a * bf2f(u1.w);
            accd[8] += a * bf2f(u2.x);  accd[9]  += a * bf2f(u2.y);
            accd[10] += a * bf2f(u2.z); accd[11] += a * bf2f(u2.w);
        } else {
            const float* dr = decoder + (size_t)sel_didx[k] * DD + lane * 12;
            const float4 f0 = *reinterpret_cast<const float4*>(dr);
            const float4 f1 = *reinterpret_cast<const float4*>(dr + 4);
            const float4 f2 = *reinterpret_cast<const float4*>(dr + 8);
            accd[0] += a * f0.x;  accd[1]  += a * f0.y;
            accd[2] += a * f0.z;  accd[3]  += a * f0.w;
            accd[4] += a * f1.x;  accd[5]  += a * f1.y;
            accd[6] += a * f1.z;  accd[7]  += a * f1.w;
            accd[8] += a * f2.x;  accd[9]  += a * f2.y;
            accd[10] += a * f2.z; accd[11] += a * f2.w;
        }
    };
    {
        int k = wv;
        for (; k + 4 < total; k += 8) { body(k); body(k + 4); }
        if (k < total) body(k);
    }

    // red overlays the arena — all reads of fv/cval are complete by here
#pragma unroll
    for (int i = 0; i < 12; ++i)
        red[wv * DD + lane * 12 + i] = accd[i];
    __syncthreads();
#pragma unroll
    for (int i = 0; i < 3; ++i) {
        const int j = t + 256 * i;
        out[(size_t)tok * DD + j] =
            red[j] + red[DD + j] + red[2 * DD + j] + red[3 * DD + j] + b_dec[j];
    }
}

// sentinel fill if workspace is too small (diagnosable: absmax ~ 12345)
__global__ void k_sentinel(float* __restrict__ out, int n) {
    int i = blockIdx.x * blockDim.x + threadIdx.x;
    if (i < n) out[i] = 12345.0f;
}

extern "C" void kernel_launch(void* const* d_in, const int* in_sizes, int n_in,
                              void* d_out, int out_size, void* d_ws, size_t ws_size,
                              hipStream_t stream)
{
    (void)in_sizes; (void)n_in;
    const float* x        = (const float*)d_in[0];
    const float* gate_W   = (const float*)d_in[1];
    const float* gate_b   = (const float*)d_in[2];
    const float* b_gate   = (const float*)d_in[3];
    const float* b_dec    = (const float*)d_in[4];
    const float* expert_W = (const float*)d_in[5];
    const float* expert_b = (const float*)d_in[6];
    const float* decoder  = (const float*)d_in[7];
    float* out = (float*)d_out;

    char* ws = (char*)d_ws;
    const size_t off_blkcnt = 256;
    const size_t off_blkoff = off_blkcnt + (size_t)NE * K1BLK * 4;
    const size_t off_rnk    = off_blkoff + (size_t)NE * K1BLK * 4;
    const size_t off_eids   = off_rnk    + (size_t)NB * 2 * 4;
    const size_t off_entw   = off_eids   + (size_t)NB * 2 * 4;
    const size_t off_lists  = off_entw   + (size_t)NB * 2 * 8;
    const size_t off_fbuf   = off_lists  + (size_t)NE * MAXT * 4;
    const size_t off_xbf    = off_fbuf   + (size_t)NB * 2 * EDD * 2;
    const size_t base_end   = off_xbf    + (size_t)NB * DD * 2;      // ~64.0 MB
    const size_t WSZ        = (size_t)NE * EDD * DD * 2;             // 37.75 MB

    if (ws_size < base_end) {
        k_sentinel<<<(out_size + 255) / 256, 256, 0, stream>>>(out, out_size);
        return;
    }
    size_t off = base_end;
    const bool have_w = (ws_size >= off + WSZ);
    unsigned short* wbf = have_w ? (unsigned short*)(ws + off) : nullptr;
    if (have_w) off += WSZ;
    const bool have_d = (ws_size >= off + WSZ);
    unsigned short* dec16v = have_d ? (unsigned short*)(ws + off) : nullptr;

    int*            counts  = (int*)ws;
    int*            blk_cnt = (int*)(ws + off_blkcnt);
    int*            blk_off = (int*)(ws + off_blkoff);
    int*            rnk     = (int*)(ws + off_rnk);
    int*            eids    = (int*)(ws + off_eids);
    double*         entw    = (double*)(ws + off_entw);
    int*            lists   = (int*)(ws + off_lists);
    unsigned short* fbuf    = (unsigned short*)(ws + off_fbuf);
    unsigned short* xbf     = (unsigned short*)(ws + off_xbf);

    hipMemsetAsync(counts, 0, 64, stream);

    k0_prep_x<<<(NB * DD / 4) / 256, 256, 0, stream>>>(x, b_dec, xbf);
    const int n4blocks = (NE * EDD * DD / 4) / 256;   // 18432
    if (have_w)
        k0_cvt_bf<<<n4blocks, 256, 0, stream>>>(expert_W, wbf);
    if (have_d)
        k0_cvt_bf<<<n4blocks, 256, 0, stream>>>(decoder, dec16v);

    k1_gate<<<K1BLK, 256, 0, stream>>>(x, gate_W, gate_b, b_gate, eids, entw, rnk, blk_cnt);
    k1_scan<<<NE, 256, 0, stream>>>(blk_cnt, blk_off, counts);
    k1_scatter<<<NB * 2 / 256, 256, 0, stream>>>(eids, rnk, blk_off, lists);

    dim3 g2(EDD / 128, MAXT / 128, NE);   // (ntile=12, mtile=64, e=16), early-exit
    if (have_w)
        k2_encode<true><<<g2, 256, 0, stream>>>(xbf, wbf, expert_W, expert_b,
                                                counts, lists, entw, fbuf);
    else
        k2_encode<false><<<g2, 256, 0, stream>>>(xbf, wbf, expert_W, expert_b,
                                                 counts, lists, entw, fbuf);

    if (have_d)
        k3_topk_decode<1><<<NB, 256, 0, stream>>>(x, b_dec, expert_W, expert_b, eids,
                                                  entw, fbuf, decoder, dec16v, out);
    else
        k3_topk_decode<0><<<NB, 256, 0, stream>>>(x, b_dec, expert_W, expert_b, eids,
                                                  entw, fbuf, decoder, dec16v, out);
}

// Round 5
// 399.689 us; speedup vs baseline: 2.8223x; 1.0694x over previous
//
#include <hip/hip_runtime.h>
#include <hip/hip_fp16.h>
#include <cstdint>
#include <cstddef>

#define NB    8192
#define DD    768
#define NE    16
#define EDD   1536
#define KTOP  100
#define MAXT  8192
#define CAND_MAX 256
#define K1BLK 2048
#define NSTEP 12
#define BKBYTES 128      // 64 k * 2B
#define CONF_ULP 21
#define BAND_ULP 20

typedef __attribute__((ext_vector_type(4))) float f32x4;
typedef __attribute__((ext_vector_type(8))) short bf16x8;

#define VMCNT8() asm volatile("s_waitcnt vmcnt(8)" ::: "memory")
#define VMCNT4() asm volatile("s_waitcnt vmcnt(4)" ::: "memory")
#define VMCNT0() asm volatile("s_waitcnt vmcnt(0)" ::: "memory")

__device__ __forceinline__ unsigned short f2bf(float v) {
    unsigned int u = __float_as_uint(v);
    u += 0x7FFFu + ((u >> 16) & 1u);   // RNE to bf16
    return (unsigned short)(u >> 16);
}
__device__ __forceinline__ float bf2f(unsigned short h) {
    return __uint_as_float(((unsigned int)h) << 16);
}
__device__ __forceinline__ unsigned short f2h_bits(float v) {
    return __half_as_ushort(__float2half(v));
}
__device__ __forceinline__ float h2f_bits(unsigned short b) {
    return __half2float(__ushort_as_half(b));
}
__device__ __forceinline__ void async16(const void* g, void* l) {
    __builtin_amdgcn_global_load_lds(
        (const __attribute__((address_space(1))) unsigned int*)g,
        (__attribute__((address_space(3))) unsigned int*)l, 16, 0, 0);
}

// ---------------------------------------------------------------- K0: converts
__global__ __launch_bounds__(256) void k0_prep_x(
    const float* __restrict__ x, const float* __restrict__ b_dec,
    unsigned short* __restrict__ xbf)
{
    const int i = blockIdx.x * 256 + threadIdx.x;      // over 1,572,864 float4s
    const float4 v = reinterpret_cast<const float4*>(x)[i];
    const float4 bd = reinterpret_cast<const float4*>(b_dec)[i % (DD / 4)];
    ushort4 h;
    h.x = f2bf(v.x - bd.x); h.y = f2bf(v.y - bd.y);
    h.z = f2bf(v.z - bd.z); h.w = f2bf(v.w - bd.w);
    reinterpret_cast<ushort4*>(xbf)[i] = h;
}

__global__ __launch_bounds__(256) void k0_cvt_bf(
    const float* __restrict__ src, unsigned short* __restrict__ dst)
{
    const int i = blockIdx.x * 256 + threadIdx.x;
    const float4 v = reinterpret_cast<const float4*>(src)[i];
    ushort4 h;
    h.x = f2bf(v.x); h.y = f2bf(v.y); h.z = f2bf(v.z); h.w = f2bf(v.w);
    reinterpret_cast<ushort4*>(dst)[i] = h;
}

// ---------------------------------------------------------------- K1a: gate
__global__ __launch_bounds__(256) void k1_gate(
    const float* __restrict__ x, const float* __restrict__ gate_W,
    const float* __restrict__ gate_b, const float* __restrict__ b_gate,
    int* __restrict__ eids, double* __restrict__ entw,
    int* __restrict__ rnk, int* __restrict__ blk_cnt,
    int* __restrict__ rnk0, int* __restrict__ blk_cnt0)
{
    __shared__ int cnt[NE];
    __shared__ int cnt0[NE];
    const int wid  = threadIdx.x >> 6;
    const int lane = threadIdx.x & 63;
    const int blk  = blockIdx.x;
    const int tok  = blk * 4 + wid;

    if (threadIdx.x < NE) { cnt[threadIdx.x] = 0; cnt0[threadIdx.x] = 0; }
    __syncthreads();

    double xv[12];
#pragma unroll
    for (int j = 0; j < 12; ++j) {
        const int k = j * 64 + lane;
        xv[j] = (double)x[(size_t)tok * DD + k] - (double)b_gate[k];
    }

    double myLogit = -1.0e300;
    for (int e = 0; e < NE; ++e) {
        double d = 0.0;
#pragma unroll
        for (int j = 0; j < 12; ++j)
            d += xv[j] * (double)gate_W[e * DD + j * 64 + lane];
#pragma unroll
        for (int off = 32; off > 0; off >>= 1)
            d += __shfl_xor(d, off);
        if (lane == e) myLogit = d + (double)gate_b[e];
    }

    double m = myLogit;
#pragma unroll
    for (int off = 8; off > 0; off >>= 1) {
        double o = __shfl_xor(m, off); m = (o > m) ? o : m;
    }
    double p = exp(myLogit - m);
    double ssum = p;
#pragma unroll
    for (int off = 8; off > 0; off >>= 1) ssum += __shfl_xor(ssum, off);
    const double score = p / ssum;

    const bool lt16 = (lane < NE);
    double m1 = score;
#pragma unroll
    for (int off = 8; off > 0; off >>= 1) {
        double o = __shfl_xor(m1, off); m1 = (o > m1) ? o : m1;
    }
    unsigned long long b0 = __ballot(lt16 && (score == m1));
    const int i0 = __ffsll(b0) - 1;
    double sc2 = (lane == i0) ? -1.0 : score;
    double m2 = sc2;
#pragma unroll
    for (int off = 8; off > 0; off >>= 1) {
        double o = __shfl_xor(m2, off); m2 = (o > m2) ? o : m2;
    }
    unsigned long long b1 = __ballot(lt16 && (sc2 == m2));
    const int i1 = __ffsll(b1) - 1;

    if (lane == 0) {
        const double w0 = 1.0 / (1.0 + exp(m2 - m1));
        const double w1 = 1.0 - w0;
        eids[tok * 2 + 0] = i0;
        eids[tok * 2 + 1] = i1;
        entw[tok * 2 + 0] = w0;
        entw[tok * 2 + 1] = w1;
        rnk[tok * 2 + 0] = atomicAdd(&cnt[i0], 1);
        rnk[tok * 2 + 1] = atomicAdd(&cnt[i1], 1);
        rnk0[tok] = atomicAdd(&cnt0[i0], 1);
    }
    __syncthreads();
    if (threadIdx.x < NE) {
        blk_cnt [threadIdx.x * K1BLK + blk] = cnt [threadIdx.x];
        blk_cnt0[threadIdx.x * K1BLK + blk] = cnt0[threadIdx.x];
    }
}

// ------------------------------------------- K1b: scan (32 blocks: 16 entry-lists, 16 slot0-order)
__global__ __launch_bounds__(256) void k1_scan(
    const int* __restrict__ bc,  int* __restrict__ bo,  int* __restrict__ counts,
    const int* __restrict__ bc0, int* __restrict__ bo0, int* __restrict__ counts0)
{
    __shared__ int tsum[256];
    const int g = blockIdx.x;
    const int e = g & 15;
    const int* src = (g >= NE) ? bc0 : bc;
    int* dst       = (g >= NE) ? bo0 : bo;
    int* cn        = (g >= NE) ? counts0 : counts;
    const int t = threadIdx.x;
    int loc[8]; int s = 0;
#pragma unroll
    for (int i = 0; i < 8; ++i) { loc[i] = s; s += src[e * K1BLK + t * 8 + i]; }
    tsum[t] = s;
    __syncthreads();
    for (int off = 1; off < 256; off <<= 1) {
        const int u = (t >= off) ? tsum[t - off] : 0;
        __syncthreads();
        tsum[t] += u;
        __syncthreads();
    }
    const int excl = tsum[t] - s;
#pragma unroll
    for (int i = 0; i < 8; ++i) dst[e * K1BLK + t * 8 + i] = excl + loc[i];
    if (t == 255) cn[e] = tsum[255];
}

// ---------------------------------------------------------------- K1c: scatter
__global__ __launch_bounds__(256) void k1_scatter(
    const int* __restrict__ eids, const int* __restrict__ rnk,
    const int* __restrict__ blk_off, int* __restrict__ lists,
    const int* __restrict__ rnk0, const int* __restrict__ blk_off0,
    const int* __restrict__ counts0, int* __restrict__ tokord)
{
    const int i = blockIdx.x * 256 + threadIdx.x;   // 16384 entries
    const int e = eids[i];
    const int blk = i >> 3;
    lists[e * MAXT + blk_off[e * K1BLK + blk] + rnk[i]] = i;
    if (!(i & 1)) {
        const int tok = i >> 1;
        int base0 = 0;
#pragma unroll
        for (int e2 = 0; e2 < NE; ++e2) base0 += (e2 < e) ? counts0[e2] : 0;
        tokord[base0 + blk_off0[e * K1BLK + blk] + rnk0[tok]] = tok;
    }
}

// ------------------------------------------------- K2: grouped expert GEMM
// pure-bf16, double-buffered LDS, all-async staging, counted vmcnt (T3+T4).
template<bool WBF>
__global__ __launch_bounds__(256, 2) void k2_encode(
    const unsigned short* __restrict__ xbf,
    const unsigned short* __restrict__ wbf,
    const float* __restrict__ expert_W,
    const float* __restrict__ expert_b,
    const int* __restrict__ counts, const int* __restrict__ lists,
    const double* __restrict__ entw, unsigned short* __restrict__ fbuf)
{
    const int e = blockIdx.z;
    const int cnt = counts[e];
    const int mbase = blockIdx.y * 128;
    if (mbase >= cnt) return;
    const int rows = min(128, cnt - mbase);
    const int nbase = blockIdx.x * 128;

    __shared__ char smem[65536];   // 2 buffers x (A 16KB | B 16KB)

    const int t = threadIdx.x;
    const int lane = t & 63;
    const int wid = t >> 6;
    const int wm = wid >> 1, wn = wid & 1;
    const int l15 = lane & 15, q = lane >> 4;
    const int rl = lane >> 3;          // row-within-8 for async staging
    const int cg = lane & 7;           // 16B chunk index
    const int xorc = (cg ^ rl) << 4;   // inverse-swizzled source chunk byte

    size_t asrc[4];
#pragma unroll
    for (int j = 0; j < 4; ++j) {
        const int r = (wid * 4 + j) * 8 + rl;
        const int rr = (r < rows) ? r : 0;
        const int tok = lists[e * MAXT + mbase + rr] >> 1;
        asrc[j] = (size_t)tok * (DD * 2) + xorc;
    }
    size_t bsrc[4];
#pragma unroll
    for (int j = 0; j < 4; ++j) {
        const int r = (wid * 4 + j) * 8 + rl;
        bsrc[j] = ((size_t)(e * EDD + nbase + r)) * (DD * 2) + xorc;
    }
    const int kq = t & 15, rg = t >> 4;   // !WBF B-convert map

    f32x4 acc[4][4];
#pragma unroll
    for (int a = 0; a < 4; ++a)
#pragma unroll
        for (int b = 0; b < 4; ++b)
            acc[a][b] = f32x4{0.f, 0.f, 0.f, 0.f};

    auto stageA = [&](int s, char* buf) {
#pragma unroll
        for (int j = 0; j < 4; ++j)
            async16((const char*)xbf + asrc[j] + (size_t)s * BKBYTES,
                    buf + ((wid * 4 + j) << 10));
    };
    auto stageB_async = [&](int s, char* buf) {
#pragma unroll
        for (int j = 0; j < 4; ++j)
            async16((const char*)wbf + bsrc[j] + (size_t)s * BKBYTES,
                    buf + 16384 + ((wid * 4 + j) << 10));
    };
    auto stageB_cvt = [&](int s, char* buf) {
#pragma unroll
        for (int j = 0; j < 8; ++j) {
            const int r = rg * 8 + j;
            const float4 bv = *reinterpret_cast<const float4*>(
                expert_W + ((size_t)e * EDD + nbase + r) * DD + s * 64 + kq * 4);
            ushort4 b4;
            b4.x = f2bf(bv.x); b4.y = f2bf(bv.y); b4.z = f2bf(bv.z); b4.w = f2bf(bv.w);
            *reinterpret_cast<ushort4*>(
                buf + 16384 + ((r * 128 + kq * 8) ^ ((r & 7) << 4))) = b4;
        }
    };
    auto compute = [&](char* buf) {
#pragma unroll
        for (int ks = 0; ks < 2; ++ks) {
            bf16x8 ah[4], bh[4];
#pragma unroll
            for (int fm = 0; fm < 4; ++fm) {
                const int row = wm * 64 + fm * 16 + l15;
                ah[fm] = *reinterpret_cast<const bf16x8*>(
                    buf + row * 128 + ((ks * 64 + q * 16) ^ ((row & 7) << 4)));
            }
#pragma unroll
            for (int fn = 0; fn < 4; ++fn) {
                const int row = wn * 64 + fn * 16 + l15;
                bh[fn] = *reinterpret_cast<const bf16x8*>(
                    buf + 16384 + row * 128 + ((ks * 64 + q * 16) ^ ((row & 7) << 4)));
            }
#pragma unroll
            for (int fm = 0; fm < 4; ++fm)
#pragma unroll
                for (int fn = 0; fn < 4; ++fn)
                    acc[fm][fn] = __builtin_amdgcn_mfma_f32_16x16x32_bf16(
                        ah[fm], bh[fn], acc[fm][fn], 0, 0, 0);
        }
    };

    // prologue: stage tile 0 into buffer 0
    if constexpr (WBF) {
        stageA(0, smem);
        stageB_async(0, smem);
    } else {
        stageB_cvt(0, smem);
        stageA(0, smem);
    }

    for (int s = 0; s < NSTEP; ++s) {
        char* cur = smem + ((s & 1) << 15);
        char* nxt = smem + (((s & 1) ^ 1) << 15);
        if (s + 1 < NSTEP) {
            if constexpr (WBF) {
                stageA(s + 1, nxt);
                stageB_async(s + 1, nxt);
                VMCNT8();              // retire tile s, keep tile s+1 in flight
            } else {
                stageB_cvt(s + 1, nxt);
                stageA(s + 1, nxt);
                VMCNT4();
            }
        } else {
            VMCNT0();
        }
        __syncthreads();
        compute(cur);
        __syncthreads();
    }

    // epilogue: C/D layout col=lane&15, row=(lane>>4)*4+reg; bias+relu+renorm; f16 out
#pragma unroll
    for (int fm = 0; fm < 4; ++fm) {
#pragma unroll
        for (int r = 0; r < 4; ++r) {
            const int ml = wm * 64 + fm * 16 + q * 4 + r;
            if (ml >= rows) continue;
            const int ent = lists[e * MAXT + mbase + ml];
            const float ren = (float)entw[ent];
            unsigned short* fout = fbuf + (size_t)ent * EDD + nbase;
#pragma unroll
            for (int fn = 0; fn < 4; ++fn) {
                const int nl = wn * 64 + fn * 16 + l15;
                float v = acc[fm][fn][r] + expert_b[e * EDD + nbase + nl];
                v = fmaxf(v, 0.f) * ren;
                fout[nl] = f2h_bits(v);
            }
        }
    }
}

// --------------------------- K3: per-token exact top-100 + fused decode
// expert-major token order + XCD-chunked dispatch for gather L2 locality.
template<int DEC16>
__global__ __launch_bounds__(256) void k3_topk_decode(
    const float* __restrict__ x, const float* __restrict__ b_dec,
    const float* __restrict__ expert_W, const float* __restrict__ expert_b,
    const int* __restrict__ eids, const double* __restrict__ entw,
    const unsigned short* __restrict__ fbuf,
    const float* __restrict__ decoder, const unsigned short* __restrict__ dec16,
    const int* __restrict__ tokord, float* __restrict__ out)
{
    // XCD-chunked: each of 8 XCDs walks a contiguous 1024-token slice of the
    // expert-major order, so its L2 holds ~2 expert dict slices.
    const int bid = blockIdx.x;
    const int tok = tokord[(bid & 7) * (NB / 8) + (bid >> 3)];
    const int t = threadIdx.x;

    // arena overlay: [fv 6144 | hist 1024 | cidx 1024 | cval 2048] before decode;
    // red[4*768 floats = 12288] after selection (fv/hist/cidx/cval all dead then).
    __shared__ __align__(16) char arena[12288];
    unsigned short* fv   = (unsigned short*)arena;
    unsigned int*   hist = (unsigned int*)(arena + 6144);
    int*            cidx = (int*)(arena + 7168);
    double*         cval = (double*)(arena + 8192);
    float*          red  = (float*)arena;
    __shared__ int hb_s, T_s, rem_s, tz_s, nsel_s, ncand_s, total_s, need_s;
    __shared__ int   sel_didx[KTOP];
    __shared__ float sel_act[KTOP];

    const unsigned int* frow = reinterpret_cast<const unsigned int*>(fbuf + (size_t)tok * 2 * EDD);
#pragma unroll
    for (int i = 0; i < 6; ++i)
        reinterpret_cast<unsigned int*>(fv)[t + 256 * i] = frow[t + 256 * i];
    if (t == 0) { tz_s = 0; nsel_s = 0; ncand_s = 0; }
    hist[t] = 0u;
    __syncthreads();

    // pass 1: top byte of f16 bits (all values >= 0)
#pragma unroll
    for (int i = 0; i < 12; ++i) {
        const unsigned int u = fv[t + 256 * i];
        if (u) atomicAdd(&hist[u >> 8], 1u);
    }
    __syncthreads();
    if (t == 0) {
        unsigned int cum = 0; int v = 255;
        for (; v >= 0; --v) { const unsigned int c = hist[v]; if (cum + c >= KTOP) break; cum += c; }
        if (v < 0) tz_s = 1;
        else { hb_s = v; rem_s = KTOP - (int)cum; }
    }
    __syncthreads();

    if (!tz_s) {
        hist[t] = 0u;
        __syncthreads();
        const unsigned int hb = (unsigned int)hb_s;
#pragma unroll
        for (int i = 0; i < 12; ++i) {
            const unsigned int u = fv[t + 256 * i];
            if (u && (u >> 8) == hb) atomicAdd(&hist[u & 255u], 1u);
        }
        __syncthreads();
        if (t == 0) {
            const int rem = rem_s; unsigned int cum = 0; int v = 255;
            for (; v >= 0; --v) { const unsigned int c = hist[v]; if (cum + c >= (unsigned int)rem) break; cum += c; }
            T_s = (hb_s << 8) | v;
        }
        __syncthreads();
    }

    if (tz_s) {
        // fewer than 100 positives: take them all (rest are exact zeros)
#pragma unroll
        for (int i = 0; i < 12; ++i) {
            const int j = t + 256 * i;
            const unsigned int u = fv[j];
            if (u) {
                const int p = atomicAdd(&nsel_s, 1);
                const int slot = (j >= EDD) ? 1 : 0;
                const int n = j - slot * EDD;
                sel_didx[p] = eids[tok * 2 + slot] * EDD + n;
                sel_act[p] = h2f_bits((unsigned short)u);
            }
        }
        __syncthreads();
        if (t == 0) total_s = nsel_s;
        __syncthreads();
    } else {
        const int T = T_s;
#pragma unroll
        for (int i = 0; i < 12; ++i) {
            const int j = t + 256 * i;
            const unsigned int u = fv[j];
            if ((int)u >= T + CONF_ULP) {
                const int p = atomicAdd(&nsel_s, 1);
                const int slot = (j >= EDD) ? 1 : 0;
                const int n = j - slot * EDD;
                sel_didx[p] = eids[tok * 2 + slot] * EDD + n;
                sel_act[p] = h2f_bits((unsigned short)u);
            } else if (u != 0u && (int)u + BAND_ULP >= T) {
                const int c = atomicAdd(&ncand_s, 1);
                if (c < CAND_MAX) cidx[c] = j;
            }
        }
        __syncthreads();

        // fp64 re-evaluation of candidates, one wave per candidate
        {
            const int ncand = min(ncand_s, CAND_MAX);
            const int wv = t >> 6, lane = t & 63;
            for (int c = wv; c < ncand; c += 4) {
                const int j = cidx[c];
                const int slot = (j >= EDD) ? 1 : 0;
                const int n = j - slot * EDD;
                const int ee = eids[tok * 2 + slot];
                const float* wr = expert_W + ((size_t)ee * EDD + n) * DD;
                const float* xr = x + (size_t)tok * DD;
                double d = 0.0;
#pragma unroll
                for (int jj = 0; jj < 12; ++jj) {
                    const int k = jj * 64 + lane;
                    d += ((double)xr[k] - (double)b_dec[k]) * (double)wr[k];
                }
#pragma unroll
                for (int off = 32; off > 0; off >>= 1) d += __shfl_xor(d, off);
                if (lane == 0) {
                    double z = d + (double)expert_b[ee * EDD + n];
                    if (z < 0.0) z = 0.0;
                    cval[c] = z * entw[tok * 2 + slot];
                }
            }
        }
        __syncthreads();
        if (t == 0) {
            const int ncand = min(ncand_s, CAND_MAX);
            int need = KTOP - nsel_s;
            if (need > ncand) need = ncand;
            if (need < 0) need = 0;
            need_s = need;
            total_s = nsel_s + need;
        }
        __syncthreads();

        // parallel rank-based selection among candidates (value desc, dict idx asc)
        {
            const int ncand = min(ncand_s, CAND_MAX);
            if (t < ncand) {
                const int j = cidx[t];
                const int slot = (j >= EDD) ? 1 : 0;
                const int my_didx = eids[tok * 2 + slot] * EDD + (j - slot * EDD);
                const double v = cval[t];
                int rank = 0;
                for (int i = 0; i < ncand; ++i) {
                    const int ji = cidx[i];
                    const int si = (ji >= EDD) ? 1 : 0;
                    const int di = eids[tok * 2 + si] * EDD + (ji - si * EDD);
                    const double vi = cval[i];
                    rank += (vi > v) || (vi == v && di < my_didx);
                }
                if (rank < need_s) {
                    sel_didx[nsel_s + rank] = my_didx;
                    sel_act[nsel_s + rank] = (float)v;
                }
            }
        }
        __syncthreads();
    }

    // fused decode: 4-wave k-split; each wave reads full rows at 24B/lane
    // (DEC16) or 48B/lane (fp32), accumulates 12 f32/lane, LDS reduce.
    const int total = total_s;
    const int wv = t >> 6;
    const int lane = t & 63;
    float accd[12];
#pragma unroll
    for (int i = 0; i < 12; ++i) accd[i] = 0.f;

    auto body = [&](int k) {
        const float a = sel_act[k];
        if (DEC16) {
            const char* dr = (const char*)(dec16 + (size_t)sel_didx[k] * DD) + lane * 24;
            const ushort4 u0 = *reinterpret_cast<const ushort4*>(dr);
            const ushort4 u1 = *reinterpret_cast<const ushort4*>(dr + 8);
            const ushort4 u2 = *reinterpret_cast<const ushort4*>(dr + 16);
            accd[0] += a * bf2f(u0.x);  accd[1]  += a * bf2f(u0.y);
            accd[2] += a * bf2f(u0.z);  accd[3]  += a * bf2f(u0.w);
            accd[4] += a * bf2f(u1.x);  accd[5]  += a * bf2f(u1.y);
            accd[6] += a * bf2f(u1.z);  accd[7]  += a * bf2f(u1.w);
            accd[8] += a * bf2f(u2.x);  accd[9]  += a * bf2f(u2.y);
            accd[10] += a * bf2f(u2.z); accd[11] += a * bf2f(u2.w);
        } else {
            const float* dr = decoder + (size_t)sel_didx[k] * DD + lane * 12;
            const float4 f0 = *reinterpret_cast<const float4*>(dr);
            const float4 f1 = *reinterpret_cast<const float4*>(dr + 4);
            const float4 f2 = *reinterpret_cast<const float4*>(dr + 8);
            accd[0] += a * f0.x;  accd[1]  += a * f0.y;
            accd[2] += a * f0.z;  accd[3]  += a * f0.w;
            accd[4] += a * f1.x;  accd[5]  += a * f1.y;
            accd[6] += a * f1.z;  accd[7]  += a * f1.w;
            accd[8] += a * f2.x;  accd[9]  += a * f2.y;
            accd[10] += a * f2.z; accd[11] += a * f2.w;
        }
    };
    {
        int k = wv;
        for (; k + 4 < total; k += 8) { body(k); body(k + 4); }
        if (k < total) body(k);
    }

    // red overlays the arena — all reads of fv/cval are complete by here
#pragma unroll
    for (int i = 0; i < 12; ++i)
        red[wv * DD + lane * 12 + i] = accd[i];
    __syncthreads();
#pragma unroll
    for (int i = 0; i < 3; ++i) {
        const int j = t + 256 * i;
        out[(size_t)tok * DD + j] =
            red[j] + red[DD + j] + red[2 * DD + j] + red[3 * DD + j] + b_dec[j];
    }
}

// sentinel fill if workspace is too small (diagnosable: absmax ~ 12345)
__global__ void k_sentinel(float* __restrict__ out, int n) {
    int i = blockIdx.x * blockDim.x + threadIdx.x;
    if (i < n) out[i] = 12345.0f;
}

extern "C" void kernel_launch(void* const* d_in, const int* in_sizes, int n_in,
                              void* d_out, int out_size, void* d_ws, size_t ws_size,
                              hipStream_t stream)
{
    (void)in_sizes; (void)n_in;
    const float* x        = (const float*)d_in[0];
    const float* gate_W   = (const float*)d_in[1];
    const float* gate_b   = (const float*)d_in[2];
    const float* b_gate   = (const float*)d_in[3];
    const float* b_dec    = (const float*)d_in[4];
    const float* expert_W = (const float*)d_in[5];
    const float* expert_b = (const float*)d_in[6];
    const float* decoder  = (const float*)d_in[7];
    float* out = (float*)d_out;

    char* ws = (char*)d_ws;
    const size_t off_counts0 = 64;
    const size_t off_blkcnt = 256;
    const size_t off_blkoff = off_blkcnt + (size_t)NE * K1BLK * 4;
    const size_t off_rnk    = off_blkoff + (size_t)NE * K1BLK * 4;
    const size_t off_eids   = off_rnk    + (size_t)NB * 2 * 4;
    const size_t off_entw   = off_eids   + (size_t)NB * 2 * 4;
    const size_t off_lists  = off_entw   + (size_t)NB * 2 * 8;
    const size_t off_fbuf   = off_lists  + (size_t)NE * MAXT * 4;
    const size_t off_xbf    = off_fbuf   + (size_t)NB * 2 * EDD * 2;
    const size_t off_bc0    = off_xbf    + (size_t)NB * DD * 2;
    const size_t off_bo0    = off_bc0    + (size_t)NE * K1BLK * 4;
    const size_t off_rnk0   = off_bo0    + (size_t)NE * K1BLK * 4;
    const size_t off_tokord = off_rnk0   + (size_t)NB * 4;
    const size_t base_end   = off_tokord + (size_t)NB * 4;           // ~64.4 MB
    const size_t WSZ        = (size_t)NE * EDD * DD * 2;             // 37.75 MB

    if (ws_size < base_end) {
        k_sentinel<<<(out_size + 255) / 256, 256, 0, stream>>>(out, out_size);
        return;
    }
    size_t off = base_end;
    const bool have_w = (ws_size >= off + WSZ);
    unsigned short* wbf = have_w ? (unsigned short*)(ws + off) : nullptr;
    if (have_w) off += WSZ;
    const bool have_d = (ws_size >= off + WSZ);
    unsigned short* dec16v = have_d ? (unsigned short*)(ws + off) : nullptr;

    int*            counts  = (int*)ws;
    int*            counts0 = (int*)(ws + off_counts0);
    int*            blk_cnt = (int*)(ws + off_blkcnt);
    int*            blk_off = (int*)(ws + off_blkoff);
    int*            rnk     = (int*)(ws + off_rnk);
    int*            eids    = (int*)(ws + off_eids);
    double*         entw    = (double*)(ws + off_entw);
    int*            lists   = (int*)(ws + off_lists);
    unsigned short* fbuf    = (unsigned short*)(ws + off_fbuf);
    unsigned short* xbf     = (unsigned short*)(ws + off_xbf);
    int*            blk_cnt0= (int*)(ws + off_bc0);
    int*            blk_off0= (int*)(ws + off_bo0);
    int*            rnk0    = (int*)(ws + off_rnk0);
    int*            tokord  = (int*)(ws + off_tokord);

    hipMemsetAsync(counts, 0, 128, stream);

    k0_prep_x<<<(NB * DD / 4) / 256, 256, 0, stream>>>(x, b_dec, xbf);
    const int n4blocks = (NE * EDD * DD / 4) / 256;   // 18432
    if (have_w)
        k0_cvt_bf<<<n4blocks, 256, 0, stream>>>(expert_W, wbf);
    if (have_d)
        k0_cvt_bf<<<n4blocks, 256, 0, stream>>>(decoder, dec16v);

    k1_gate<<<K1BLK, 256, 0, stream>>>(x, gate_W, gate_b, b_gate, eids, entw,
                                       rnk, blk_cnt, rnk0, blk_cnt0);
    k1_scan<<<2 * NE, 256, 0, stream>>>(blk_cnt, blk_off, counts,
                                        blk_cnt0, blk_off0, counts0);
    k1_scatter<<<NB * 2 / 256, 256, 0, stream>>>(eids, rnk, blk_off, lists,
                                                 rnk0, blk_off0, counts0, tokord);

    dim3 g2(EDD / 128, MAXT / 128, NE);   // (ntile=12, mtile=64, e=16), early-exit
    if (have_w)
        k2_encode<true><<<g2, 256, 0, stream>>>(xbf, wbf, expert_W, expert_b,
                                                counts, lists, entw, fbuf);
    else
        k2_encode<false><<<g2, 256, 0, stream>>>(xbf, wbf, expert_W, expert_b,
                                                 counts, lists, entw, fbuf);

    if (have_d)
        k3_topk_decode<1><<<NB, 256, 0, stream>>>(x, b_dec, expert_W, expert_b, eids,
                                                  entw, fbuf, decoder, dec16v, tokord, out);
    else
        k3_topk_decode<0><<<NB, 256, 0, stream>>>(x, b_dec, expert_W, expert_b, eids,
                                                  entw, fbuf, decoder, dec16v, tokord, out);
}